// Round 1
// baseline (1781.763 us; speedup 1.0000x reference)
//
#include <hip/hip_runtime.h>
#include <cstdint>
#include <cstddef>

#define THREADS 256

// ---------------------------------------------------------------------------
// JAX threefry2x32 (Random123, 20 rounds) — used for the dropout masks.
// Harness JAX assumed to have jax_threefry_partitionable=True (default since
// late-2024 JAX): split keys = tf(key,(0,j)); bits[i] = o0^o1 of tf(key,(0,i)).
// ---------------------------------------------------------------------------
__host__ __device__ __forceinline__ void tf2x32(unsigned k0, unsigned k1,
                                                unsigned x0, unsigned x1,
                                                unsigned* o0, unsigned* o1) {
  unsigned ks2 = k0 ^ k1 ^ 0x1BD11BDAu;
  x0 += k0; x1 += k1;
#define TFR(r) { x0 += x1; x1 = (x1 << (r)) | (x1 >> (32 - (r))); x1 ^= x0; }
  TFR(13) TFR(15) TFR(26) TFR(6)   x0 += k1;  x1 += ks2 + 1u;
  TFR(17) TFR(29) TFR(16) TFR(24)  x0 += ks2; x1 += k0 + 2u;
  TFR(13) TFR(15) TFR(26) TFR(6)   x0 += k0;  x1 += k1 + 3u;
  TFR(17) TFR(29) TFR(16) TFR(24)  x0 += k1;  x1 += ks2 + 4u;
  TFR(13) TFR(15) TFR(26) TFR(6)   x0 += ks2; x1 += k0 + 5u;
#undef TFR
  *o0 = x0; *o1 = x1;
}

// ---------------------------------------------------------------------------
// CSR build (bucket edges by dst). Order within a node is arbitrary (atomic),
// which only perturbs fp32 sum order (~1e-6).
// ---------------------------------------------------------------------------
__global__ __launch_bounds__(THREADS) void compute_deg(const int* __restrict__ dst,
                                                       int* __restrict__ deg, int E) {
  int e = blockIdx.x * THREADS + threadIdx.x;
  if (e < E) atomicAdd(&deg[dst[e]], 1);
}

// Per-block inclusive scan + one global atomic → contiguous per-node segments
// (segment order across blocks arbitrary; aggregation only needs start+deg).
__global__ __launch_bounds__(THREADS) void alloc_starts(const int* __restrict__ deg,
                                                        int* __restrict__ start,
                                                        int* __restrict__ counter, int n) {
  __shared__ int sdata[THREADS];
  __shared__ int sbase;
  int i = blockIdx.x * THREADS + threadIdx.x;
  int d = (i < n) ? deg[i] : 0;
  sdata[threadIdx.x] = d;
  __syncthreads();
  for (int off = 1; off < THREADS; off <<= 1) {
    int v = (threadIdx.x >= off) ? sdata[threadIdx.x - off] : 0;
    __syncthreads();
    sdata[threadIdx.x] += v;
    __syncthreads();
  }
  if (threadIdx.x == THREADS - 1) sbase = atomicAdd(counter, sdata[THREADS - 1]);
  __syncthreads();
  if (i < n) start[i] = sbase + sdata[threadIdx.x] - d;  // exclusive
}

__global__ __launch_bounds__(THREADS) void fill_csr(const int* __restrict__ src,
                                                    const int* __restrict__ dst,
                                                    const int* __restrict__ start,
                                                    int* __restrict__ fill,
                                                    int* __restrict__ colbuf, int E) {
  int e = blockIdx.x * THREADS + threadIdx.x;
  if (e >= E) return;
  int d = dst[e];
  int p = atomicAdd(&fill[d], 1);
  colbuf[start[d] + p] = src[e];
}

// ---------------------------------------------------------------------------
// fp32 GEMM: C[M][128] = A[M][128] @ W[128][128] (+ bias).
// 64-row tile, full 128 cols, BK=32, LDS A stored [k][row] (stride 66: the
// +2 pad keeps float2 reads aligned and staging stores 2-way-free).
// Safe for in-place A==C: each block only writes its own rows, after K-loop.
// ---------------------------------------------------------------------------
__global__ __launch_bounds__(THREADS) void gemm128(const float* A,
                                                   const float* __restrict__ W,
                                                   const float* __restrict__ bias,
                                                   float* C, int M) {
  __shared__ __align__(16) float As[32][66];   // [k][row]
  __shared__ __align__(16) float Bs[32][128];  // [k][col]
  int t = threadIdx.x;
  int row0 = blockIdx.x * 64;
  int tx = t & 31;   // col group: cols tx*4..+3
  int ty = t >> 5;   // 0..7 → rows ty*8..+7
  float acc[8][4];
#pragma unroll
  for (int i = 0; i < 8; ++i)
#pragma unroll
    for (int j = 0; j < 4; ++j) acc[i][j] = 0.f;

  for (int k0 = 0; k0 < 128; k0 += 32) {
    // stage A chunk: 64 rows x 32 k, scalar loads (coalesced 128B/32 lanes)
#pragma unroll
    for (int i = 0; i < 8; ++i) {
      int lin = t + i * THREADS;        // 0..2047
      int r = lin >> 5;
      int k = lin & 31;
      int grow = row0 + r;
      As[k][r] = (grow < M) ? A[(size_t)grow * 128 + k0 + k] : 0.f;
    }
    // stage B chunk: 32 x 128 via float4 (coalesced)
#pragma unroll
    for (int i = 0; i < 4; ++i) {
      int lin = t + i * THREADS;        // 0..1023 float4 ids
      int k = lin >> 5;
      int c = (lin & 31) << 2;
      *(float4*)&Bs[k][c] = *(const float4*)(W + (size_t)(k0 + k) * 128 + c);
    }
    __syncthreads();
#pragma unroll
    for (int k = 0; k < 32; ++k) {
      float4 b = *(const float4*)&Bs[k][tx << 2];
      float a[8];
      *(float2*)&a[0] = *(const float2*)&As[k][ty * 8 + 0];
      *(float2*)&a[2] = *(const float2*)&As[k][ty * 8 + 2];
      *(float2*)&a[4] = *(const float2*)&As[k][ty * 8 + 4];
      *(float2*)&a[6] = *(const float2*)&As[k][ty * 8 + 6];
#pragma unroll
      for (int i = 0; i < 8; ++i) {
        acc[i][0] += a[i] * b.x;
        acc[i][1] += a[i] * b.y;
        acc[i][2] += a[i] * b.z;
        acc[i][3] += a[i] * b.w;
      }
    }
    __syncthreads();
  }
  float4 bb = make_float4(0.f, 0.f, 0.f, 0.f);
  if (bias) bb = *(const float4*)(bias + (tx << 2));
#pragma unroll
  for (int i = 0; i < 8; ++i) {
    int grow = row0 + ty * 8 + i;
    if (grow < M) {
      float4 o;
      o.x = acc[i][0] + bb.x;
      o.y = acc[i][1] + bb.y;
      o.z = acc[i][2] + bb.z;
      o.w = acc[i][3] + bb.w;
      *(float4*)(C + (size_t)grow * 128 + (tx << 2)) = o;
    }
  }
}

// fp32 GEMM: C[M][16] = A[M][128] @ W[128][16] (+ bias). W fully in LDS.
__global__ __launch_bounds__(THREADS) void gemm16(const float* __restrict__ A,
                                                  const float* __restrict__ W,
                                                  const float* __restrict__ bias,
                                                  float* __restrict__ C, int M) {
  __shared__ __align__(16) float Bs[128][16];
  __shared__ __align__(16) float As[32][66];
  int t = threadIdx.x;
#pragma unroll
  for (int i = 0; i < 8; ++i) {
    int lin = t + i * THREADS;          // 0..2047
    Bs[lin >> 4][lin & 15] = W[lin];
  }
  int row0 = blockIdx.x * 64;
  int tx = t & 15;   // col
  int ty = t >> 4;   // 0..15 → rows ty*4..+3
  float acc[4] = {0.f, 0.f, 0.f, 0.f};
  __syncthreads();
  for (int k0 = 0; k0 < 128; k0 += 32) {
#pragma unroll
    for (int i = 0; i < 8; ++i) {
      int lin = t + i * THREADS;
      int r = lin >> 5;
      int k = lin & 31;
      int grow = row0 + r;
      As[k][r] = (grow < M) ? A[(size_t)grow * 128 + k0 + k] : 0.f;
    }
    __syncthreads();
#pragma unroll
    for (int k = 0; k < 32; ++k) {
      float b = Bs[k0 + k][tx];
#pragma unroll
      for (int i = 0; i < 4; ++i) acc[i] += As[k][ty * 4 + i] * b;
    }
    __syncthreads();
  }
  float bb = bias ? bias[tx] : 0.f;
#pragma unroll
  for (int i = 0; i < 4; ++i) {
    int grow = row0 + ty * 4 + i;
    if (grow < M) C[(size_t)grow * 16 + tx] = acc[i] + bb;
  }
}

// ---------------------------------------------------------------------------
// Z[n] += agg(Y)[n] / max(deg,1): one wave per node, float2/lane (512B rows).
// ---------------------------------------------------------------------------
__global__ __launch_bounds__(THREADS) void aggregate128(const float* __restrict__ Y,
                                                        float* __restrict__ Z,
                                                        const int* __restrict__ colbuf,
                                                        const int* __restrict__ start,
                                                        const int* __restrict__ deg,
                                                        int nnodes) {
  int w = (blockIdx.x * THREADS + threadIdx.x) >> 6;  // node = global wave id
  int lane = threadIdx.x & 63;
  if (w >= nnodes) return;
  int s0 = start[w];
  int dg = deg[w];
  float2 acc = {0.f, 0.f};
  int s_next = (dg > 0) ? colbuf[s0] : 0;
  for (int i = 0; i < dg; ++i) {
    int s = s_next;
    if (i + 1 < dg) s_next = colbuf[s0 + i + 1];   // prefetch next edge id
    float2 v = *(const float2*)(Y + (size_t)s * 128 + (lane << 1));
    acc.x += v.x;
    acc.y += v.y;
  }
  float sc = 1.0f / fmaxf((float)dg, 1.0f);
  size_t off = (size_t)w * 128 + (lane << 1);
  float2 z = *(const float2*)(Z + off);
  z.x += acc.x * sc;
  z.y += acc.y * sc;
  *(float2*)(Z + off) = z;
}

// Out[n][c] += agg(Y16)[n][c] / max(deg,1): 16 threads per node.
__global__ __launch_bounds__(THREADS) void aggregate16(const float* __restrict__ Y,
                                                       float* __restrict__ Out,
                                                       const int* __restrict__ colbuf,
                                                       const int* __restrict__ start,
                                                       const int* __restrict__ deg,
                                                       int nnodes) {
  int gid = blockIdx.x * THREADS + threadIdx.x;
  int n = gid >> 4;
  int c = gid & 15;
  if (n >= nnodes) return;
  int s0 = start[n];
  int dg = deg[n];
  float acc = 0.f;
  for (int i = 0; i < dg; ++i) {
    int s = colbuf[s0 + i];
    acc += Y[(size_t)s * 16 + c];
  }
  float sc = 1.0f / fmaxf((float)dg, 1.0f);
  Out[(size_t)n * 16 + c] += acc * sc;
}

// ---------------------------------------------------------------------------
// BN: column sums/sumsq → scale/shift → fused affine+ReLU+dropout (in place).
// ---------------------------------------------------------------------------
__global__ __launch_bounds__(THREADS) void bn_stats(const float* __restrict__ H,
                                                    float* __restrict__ sums, int n) {
  int col = threadIdx.x & 127;
  int half = threadIdx.x >> 7;  // 0/1
  float s = 0.f, sq = 0.f;
  for (int r = blockIdx.x * 2 + half; r < n; r += gridDim.x * 2) {
    float v = H[(size_t)r * 128 + col];
    s += v;
    sq += v * v;
  }
  __shared__ float ls[THREADS], lq[THREADS];
  ls[threadIdx.x] = s;
  lq[threadIdx.x] = sq;
  __syncthreads();
  if (half == 0) {
    s += ls[col + 128];
    sq += lq[col + 128];
    atomicAdd(&sums[col], s);
    atomicAdd(&sums[128 + col], sq);
  }
}

__global__ void bn_finalize(const float* __restrict__ sums,
                            const float* __restrict__ g,
                            const float* __restrict__ be,
                            float* __restrict__ scsh, float n) {
  int c = threadIdx.x;  // 128 threads
  float mu = sums[c] / n;
  float var = sums[128 + c] / n - mu * mu;
  float inv = rsqrtf(var + 1e-5f);
  float sc = g[c] * inv;
  scsh[c] = sc;
  scsh[128 + c] = be[c] - mu * sc;
}

// keep[i] = msb(o0^o1 of tf(key,(0,i))) == 0  (uniform<0.5, partitionable).
// H[i] = keep ? 2*relu(H[i]*scale+shift) : 0. Two elements (float2) / thread.
__global__ __launch_bounds__(THREADS) void bn_relu_dropout(float* __restrict__ H,
                                                           const float* __restrict__ scsh,
                                                           unsigned k0, unsigned k1,
                                                           int count2) {
  int j = blockIdx.x * THREADS + threadIdx.x;  // element pair id
  if (j >= count2) return;
  unsigned i0 = (unsigned)j << 1;
  unsigned a0, a1, b0, b1;
  tf2x32(k0, k1, 0u, i0, &a0, &a1);
  tf2x32(k0, k1, 0u, i0 + 1u, &b0, &b1);
  int col = (int)(i0 & 127u);  // even
  float2 v = *(float2*)(H + i0);
  float s0 = scsh[col], sh0 = scsh[128 + col];
  float s1 = scsh[col + 1], sh1 = scsh[129 + col];
  v.x = fmaxf(v.x * s0 + sh0, 0.f);
  v.y = fmaxf(v.y * s1 + sh1, 0.f);
  v.x = ((a0 ^ a1) >> 31) ? 0.f : 2.f * v.x;
  v.y = ((b0 ^ b1) >> 31) ? 0.f : 2.f * v.y;
  *(float2*)(H + i0) = v;
}

// ---------------------------------------------------------------------------
// Launch: CSR once; per layer GEMM(Wl)→buf0, GEMM(Wr)+b→h, gather-agg into h,
// BN stats/finalize, fused BN+ReLU+dropout. Layer-3 aggregates the 16-dim
// projection. ws use: 2×N×128 f32 (102 MB) + CSR (~8 MB).
// ---------------------------------------------------------------------------
extern "C" void kernel_launch(void* const* d_in, const int* in_sizes, int n_in,
                              void* d_out, int out_size, void* d_ws, size_t ws_size,
                              hipStream_t stream) {
  const float* x   = (const float*)d_in[0];
  const int* eidx  = (const int*)d_in[1];
  const float* W1l = (const float*)d_in[2];
  const float* W1r = (const float*)d_in[3];
  const float* b1  = (const float*)d_in[4];
  const float* g1  = (const float*)d_in[5];
  const float* be1 = (const float*)d_in[6];
  const float* W2l = (const float*)d_in[7];
  const float* W2r = (const float*)d_in[8];
  const float* b2  = (const float*)d_in[9];
  const float* g2  = (const float*)d_in[10];
  const float* be2 = (const float*)d_in[11];
  const float* W3l = (const float*)d_in[12];
  const float* W3r = (const float*)d_in[13];
  const float* b3  = (const float*)d_in[14];
  float* out = (float*)d_out;

  const int N = in_sizes[0] / 128;
  const int E = in_sizes[1] / 2;
  const int* esrc = eidx;
  const int* edst = eidx + E;

  size_t N128 = (size_t)N * 128;
  float* buf0 = (float*)d_ws;
  float* buf1 = buf0 + N128;
  float* sums = buf1 + N128;
  float* scsh = sums + 256;
  int* ideg   = (int*)(scsh + 256);
  int* istart = ideg + N;
  int* ifill  = istart + N;
  int* icnt   = ifill + N;
  int* icol   = icnt + 4;

  // dropout keys: k1,k2 = split(key(42)) under partitionable threefry
  unsigned k1a, k1b, k2a, k2b;
  tf2x32(0u, 42u, 0u, 0u, &k1a, &k1b);
  tf2x32(0u, 42u, 0u, 1u, &k2a, &k2b);

  hipMemsetAsync(ideg, 0, (size_t)N * 4, stream);
  hipMemsetAsync(ifill, 0, (size_t)N * 4, stream);
  hipMemsetAsync(icnt, 0, 16, stream);

  int gE = (E + THREADS - 1) / THREADS;
  int gN = (N + THREADS - 1) / THREADS;
  compute_deg<<<gE, THREADS, 0, stream>>>(edst, ideg, E);
  alloc_starts<<<gN, THREADS, 0, stream>>>(ideg, istart, icnt, N);
  fill_csr<<<gE, THREADS, 0, stream>>>(esrc, edst, istart, ifill, icol, E);

  int gM = (N + 63) / 64;
  int gW = (N + 3) / 4;                 // aggregate128: 4 waves/block
  int half2 = (int)(N128 / 2);
  int gD = (half2 + THREADS - 1) / THREADS;
  int gA16 = (N * 16 + THREADS - 1) / THREADS;

  // ---- Layer 1 ----
  gemm128<<<gM, THREADS, 0, stream>>>(x, W1l, nullptr, buf0, N);
  gemm128<<<gM, THREADS, 0, stream>>>(x, W1r, b1, buf1, N);
  aggregate128<<<gW, THREADS, 0, stream>>>(buf0, buf1, icol, istart, ideg, N);
  hipMemsetAsync(sums, 0, 256 * 4, stream);
  bn_stats<<<200, THREADS, 0, stream>>>(buf1, sums, N);
  bn_finalize<<<1, 128, 0, stream>>>(sums, g1, be1, scsh, (float)N);
  bn_relu_dropout<<<gD, THREADS, 0, stream>>>(buf1, scsh, k1a, k1b, half2);

  // ---- Layer 2 ----
  gemm128<<<gM, THREADS, 0, stream>>>(buf1, W2l, nullptr, buf0, N);
  gemm128<<<gM, THREADS, 0, stream>>>(buf1, W2r, b2, buf1, N);  // in-place: block writes only its own rows, post K-loop
  aggregate128<<<gW, THREADS, 0, stream>>>(buf0, buf1, icol, istart, ideg, N);
  hipMemsetAsync(sums, 0, 256 * 4, stream);
  bn_stats<<<200, THREADS, 0, stream>>>(buf1, sums, N);
  bn_finalize<<<1, 128, 0, stream>>>(sums, g2, be2, scsh, (float)N);
  bn_relu_dropout<<<gD, THREADS, 0, stream>>>(buf1, scsh, k2a, k2b, half2);

  // ---- Layer 3 (project to 16 first, then aggregate: 4x cheaper agg) ----
  gemm16<<<gM, THREADS, 0, stream>>>(buf1, W3l, nullptr, buf0, N);
  gemm16<<<gM, THREADS, 0, stream>>>(buf1, W3r, b3, out, N);
  aggregate16<<<gA16, THREADS, 0, stream>>>(buf0, out, icol, istart, ideg, N);
}

// Round 2
// 1066.576 us; speedup vs baseline: 1.6705x; 1.6705x over previous
//
#include <hip/hip_runtime.h>
#include <cstdint>
#include <cstddef>

#define THREADS 256

// ---------------------------------------------------------------------------
// JAX threefry2x32 (Random123, 20 rounds) — used for the dropout masks.
// jax_threefry_partitionable=True semantics (verified R1: absmax 0.0156):
// split keys = tf(key,(0,j)); bits[i] = o0^o1 of tf(key,(0,i)).
// ---------------------------------------------------------------------------
__host__ __device__ __forceinline__ void tf2x32(unsigned k0, unsigned k1,
                                                unsigned x0, unsigned x1,
                                                unsigned* o0, unsigned* o1) {
  unsigned ks2 = k0 ^ k1 ^ 0x1BD11BDAu;
  x0 += k0; x1 += k1;
#define TFR(r) { x0 += x1; x1 = (x1 << (r)) | (x1 >> (32 - (r))); x1 ^= x0; }
  TFR(13) TFR(15) TFR(26) TFR(6)   x0 += k1;  x1 += ks2 + 1u;
  TFR(17) TFR(29) TFR(16) TFR(24)  x0 += ks2; x1 += k0 + 2u;
  TFR(13) TFR(15) TFR(26) TFR(6)   x0 += k0;  x1 += k1 + 3u;
  TFR(17) TFR(29) TFR(16) TFR(24)  x0 += k1;  x1 += ks2 + 4u;
  TFR(13) TFR(15) TFR(26) TFR(6)   x0 += ks2; x1 += k0 + 5u;
#undef TFR
  *o0 = x0; *o1 = x1;
}

// ---------------------------------------------------------------------------
// CSR build (bucket edges by dst). Order within a node is arbitrary (atomic),
// which only perturbs fp32 sum order (~1e-6).
// ---------------------------------------------------------------------------
__global__ __launch_bounds__(THREADS) void compute_deg(const int* __restrict__ dst,
                                                       int* __restrict__ deg, int E) {
  int e = blockIdx.x * THREADS + threadIdx.x;
  if (e < E) atomicAdd(&deg[dst[e]], 1);
}

// Per-block inclusive scan + one global atomic → contiguous per-node segments
// (segment order across blocks arbitrary; aggregation only needs start+deg).
__global__ __launch_bounds__(THREADS) void alloc_starts(const int* __restrict__ deg,
                                                        int* __restrict__ start,
                                                        int* __restrict__ counter, int n) {
  __shared__ int sdata[THREADS];
  __shared__ int sbase;
  int i = blockIdx.x * THREADS + threadIdx.x;
  int d = (i < n) ? deg[i] : 0;
  sdata[threadIdx.x] = d;
  __syncthreads();
  for (int off = 1; off < THREADS; off <<= 1) {
    int v = (threadIdx.x >= off) ? sdata[threadIdx.x - off] : 0;
    __syncthreads();
    sdata[threadIdx.x] += v;
    __syncthreads();
  }
  if (threadIdx.x == THREADS - 1) sbase = atomicAdd(counter, sdata[THREADS - 1]);
  __syncthreads();
  if (i < n) start[i] = sbase + sdata[threadIdx.x] - d;  // exclusive
}

__global__ __launch_bounds__(THREADS) void fill_csr(const int* __restrict__ src,
                                                    const int* __restrict__ dst,
                                                    const int* __restrict__ start,
                                                    int* __restrict__ fill,
                                                    int* __restrict__ colbuf, int E) {
  int e = blockIdx.x * THREADS + threadIdx.x;
  if (e >= E) return;
  int d = dst[e];
  int p = atomicAdd(&fill[d], 1);
  colbuf[start[d] + p] = src[e];
}

// ---------------------------------------------------------------------------
// fp32 GEMM: C[M][128] = A[M][128] @ W[128][128] (+ bias).
// 64-row tile, full 128 cols, BK=32, LDS A stored [k][row].
// Safe for in-place A==C: each block only writes its own rows, after K-loop.
// ---------------------------------------------------------------------------
__global__ __launch_bounds__(THREADS) void gemm128(const float* A,
                                                   const float* __restrict__ W,
                                                   const float* __restrict__ bias,
                                                   float* C, int M) {
  __shared__ __align__(16) float As[32][66];   // [k][row]
  __shared__ __align__(16) float Bs[32][128];  // [k][col]
  int t = threadIdx.x;
  int row0 = blockIdx.x * 64;
  int tx = t & 31;   // col group: cols tx*4..+3
  int ty = t >> 5;   // 0..7 → rows ty*8..+7
  float acc[8][4];
#pragma unroll
  for (int i = 0; i < 8; ++i)
#pragma unroll
    for (int j = 0; j < 4; ++j) acc[i][j] = 0.f;

  for (int k0 = 0; k0 < 128; k0 += 32) {
    // stage A chunk: 64 rows x 32 k, scalar loads (coalesced 128B/32 lanes)
#pragma unroll
    for (int i = 0; i < 8; ++i) {
      int lin = t + i * THREADS;        // 0..2047
      int r = lin >> 5;
      int k = lin & 31;
      int grow = row0 + r;
      As[k][r] = (grow < M) ? A[(size_t)grow * 128 + k0 + k] : 0.f;
    }
    // stage B chunk: 32 x 128 via float4 (coalesced)
#pragma unroll
    for (int i = 0; i < 4; ++i) {
      int lin = t + i * THREADS;        // 0..1023 float4 ids
      int k = lin >> 5;
      int c = (lin & 31) << 2;
      *(float4*)&Bs[k][c] = *(const float4*)(W + (size_t)(k0 + k) * 128 + c);
    }
    __syncthreads();
#pragma unroll
    for (int k = 0; k < 32; ++k) {
      float4 b = *(const float4*)&Bs[k][tx << 2];
      float a[8];
      *(float2*)&a[0] = *(const float2*)&As[k][ty * 8 + 0];
      *(float2*)&a[2] = *(const float2*)&As[k][ty * 8 + 2];
      *(float2*)&a[4] = *(const float2*)&As[k][ty * 8 + 4];
      *(float2*)&a[6] = *(const float2*)&As[k][ty * 8 + 6];
#pragma unroll
      for (int i = 0; i < 8; ++i) {
        acc[i][0] += a[i] * b.x;
        acc[i][1] += a[i] * b.y;
        acc[i][2] += a[i] * b.z;
        acc[i][3] += a[i] * b.w;
      }
    }
    __syncthreads();
  }
  float4 bb = make_float4(0.f, 0.f, 0.f, 0.f);
  if (bias) bb = *(const float4*)(bias + (tx << 2));
#pragma unroll
  for (int i = 0; i < 8; ++i) {
    int grow = row0 + ty * 8 + i;
    if (grow < M) {
      float4 o;
      o.x = acc[i][0] + bb.x;
      o.y = acc[i][1] + bb.y;
      o.z = acc[i][2] + bb.z;
      o.w = acc[i][3] + bb.w;
      *(float4*)(C + (size_t)grow * 128 + (tx << 2)) = o;
    }
  }
}

// ---------------------------------------------------------------------------
// Fused layer-3 projections: Cl = A@Wl, Cr = A@Wr + br. Reads A ONCE.
// R1 post-mortem: the previous split gemm16 hit a 256-VGPR spill cliff
// (445 MB fetch / 430 MB write of scratch traffic, 385 µs/dispatch).
// Fix: 1 (row,col) pair per thread → 2 live accumulators, unroll capped at 4.
// ---------------------------------------------------------------------------
__global__ __launch_bounds__(THREADS) void gemm16_dual(const float* __restrict__ A,
                                                       const float* __restrict__ Wl,
                                                       const float* __restrict__ Wr,
                                                       const float* __restrict__ br,
                                                       float* __restrict__ Cl,
                                                       float* __restrict__ Cr, int M) {
  __shared__ __align__(16) float Wls[128][16];  // [k][col]
  __shared__ __align__(16) float Wrs[128][16];
  __shared__ __align__(16) float As[16][130];   // [row][k], +2 pad
  int t = threadIdx.x;
  // stage both weight matrices (2048 floats each) as float4, linear
#pragma unroll
  for (int i = 0; i < 2; ++i) {
    int lin = (t + i * THREADS) << 2;           // float4 id → float offset
    *(float4*)&Wls[0][lin & 2047] = *(const float4*)(Wl + lin);
    *(float4*)&Wrs[0][lin & 2047] = *(const float4*)(Wr + lin);
  }
  int row0 = blockIdx.x * 16;
  int r = t >> 4;     // 0..15 local row
  int c = t & 15;     // col / chunk id
  // stage A tile: thread (r,c) loads A[row0+r][c*8 .. c*8+7]
  {
    int grow = row0 + r;
    float4 v0 = make_float4(0.f, 0.f, 0.f, 0.f), v1 = v0;
    if (grow < M) {
      const float* ap = A + (size_t)grow * 128 + c * 8;
      v0 = *(const float4*)(ap);
      v1 = *(const float4*)(ap + 4);
    }
    *(float4*)&As[r][c * 8] = v0;
    *(float4*)&As[r][c * 8 + 4] = v1;
  }
  __syncthreads();
  float accl = 0.f, accr = 0.f;
#pragma unroll 4
  for (int k = 0; k < 128; ++k) {
    float a = As[r][k];                          // broadcast across 16 lanes
    accl += a * Wls[k][c];
    accr += a * Wrs[k][c];
  }
  int grow = row0 + r;
  if (grow < M) {
    Cl[(size_t)grow * 16 + c] = accl;
    Cr[(size_t)grow * 16 + c] = accr + br[c];
  }
}

// ---------------------------------------------------------------------------
// Z[n] += agg(Y)[n] / max(deg,1): one wave per node, float2/lane (512B rows).
// ---------------------------------------------------------------------------
__global__ __launch_bounds__(THREADS) void aggregate128(const float* __restrict__ Y,
                                                        float* __restrict__ Z,
                                                        const int* __restrict__ colbuf,
                                                        const int* __restrict__ start,
                                                        const int* __restrict__ deg,
                                                        int nnodes) {
  int w = (blockIdx.x * THREADS + threadIdx.x) >> 6;  // node = global wave id
  int lane = threadIdx.x & 63;
  if (w >= nnodes) return;
  int s0 = start[w];
  int dg = deg[w];
  float2 acc = {0.f, 0.f};
  int s_next = (dg > 0) ? colbuf[s0] : 0;
  for (int i = 0; i < dg; ++i) {
    int s = s_next;
    if (i + 1 < dg) s_next = colbuf[s0 + i + 1];   // prefetch next edge id
    float2 v = *(const float2*)(Y + (size_t)s * 128 + (lane << 1));
    acc.x += v.x;
    acc.y += v.y;
  }
  float sc = 1.0f / fmaxf((float)dg, 1.0f);
  size_t off = (size_t)w * 128 + (lane << 1);
  float2 z = *(const float2*)(Z + off);
  z.x += acc.x * sc;
  z.y += acc.y * sc;
  *(float2*)(Z + off) = z;
}

// Out[n][c] += agg(Y16)[n][c] / max(deg,1): 16 threads per node.
__global__ __launch_bounds__(THREADS) void aggregate16(const float* __restrict__ Y,
                                                       float* __restrict__ Out,
                                                       const int* __restrict__ colbuf,
                                                       const int* __restrict__ start,
                                                       const int* __restrict__ deg,
                                                       int nnodes) {
  int gid = blockIdx.x * THREADS + threadIdx.x;
  int n = gid >> 4;
  int c = gid & 15;
  if (n >= nnodes) return;
  int s0 = start[n];
  int dg = deg[n];
  float acc = 0.f;
  for (int i = 0; i < dg; ++i) {
    int s = colbuf[s0 + i];
    acc += Y[(size_t)s * 16 + c];
  }
  float sc = 1.0f / fmaxf((float)dg, 1.0f);
  Out[(size_t)n * 16 + c] += acc * sc;
}

// ---------------------------------------------------------------------------
// BN: column sums/sumsq → scale/shift → fused affine+ReLU+dropout (in place).
// ---------------------------------------------------------------------------
__global__ __launch_bounds__(THREADS) void bn_stats(const float* __restrict__ H,
                                                    float* __restrict__ sums, int n) {
  int col = threadIdx.x & 127;
  int half = threadIdx.x >> 7;  // 0/1
  float s = 0.f, sq = 0.f;
  for (int r = blockIdx.x * 2 + half; r < n; r += gridDim.x * 2) {
    float v = H[(size_t)r * 128 + col];
    s += v;
    sq += v * v;
  }
  __shared__ float ls[THREADS], lq[THREADS];
  ls[threadIdx.x] = s;
  lq[threadIdx.x] = sq;
  __syncthreads();
  if (half == 0) {
    s += ls[col + 128];
    sq += lq[col + 128];
    atomicAdd(&sums[col], s);
    atomicAdd(&sums[128 + col], sq);
  }
}

__global__ void bn_finalize(const float* __restrict__ sums,
                            const float* __restrict__ g,
                            const float* __restrict__ be,
                            float* __restrict__ scsh, float n) {
  int c = threadIdx.x;  // 128 threads
  float mu = sums[c] / n;
  float var = sums[128 + c] / n - mu * mu;
  float inv = rsqrtf(var + 1e-5f);
  float sc = g[c] * inv;
  scsh[c] = sc;
  scsh[128 + c] = be[c] - mu * sc;
}

// keep[i] = msb(o0^o1 of tf(key,(0,i))) == 0  (uniform<0.5, partitionable).
// H[i] = keep ? 2*relu(H[i]*scale+shift) : 0. Two elements (float2) / thread.
__global__ __launch_bounds__(THREADS) void bn_relu_dropout(float* __restrict__ H,
                                                           const float* __restrict__ scsh,
                                                           unsigned k0, unsigned k1,
                                                           int count2) {
  int j = blockIdx.x * THREADS + threadIdx.x;  // element pair id
  if (j >= count2) return;
  unsigned i0 = (unsigned)j << 1;
  unsigned a0, a1, b0, b1;
  tf2x32(k0, k1, 0u, i0, &a0, &a1);
  tf2x32(k0, k1, 0u, i0 + 1u, &b0, &b1);
  int col = (int)(i0 & 127u);  // even
  float2 v = *(float2*)(H + i0);
  float s0 = scsh[col], sh0 = scsh[128 + col];
  float s1 = scsh[col + 1], sh1 = scsh[129 + col];
  v.x = fmaxf(v.x * s0 + sh0, 0.f);
  v.y = fmaxf(v.y * s1 + sh1, 0.f);
  v.x = ((a0 ^ a1) >> 31) ? 0.f : 2.f * v.x;
  v.y = ((b0 ^ b1) >> 31) ? 0.f : 2.f * v.y;
  *(float2*)(H + i0) = v;
}

// ---------------------------------------------------------------------------
// Launch: CSR once; per layer GEMM(Wl)→buf0, GEMM(Wr)+b→h, gather-agg into h,
// BN stats/finalize, fused BN+ReLU+dropout. Layer-3 projects to 16 (fused
// dual GEMM, reads A once) then aggregates the 16-dim projection.
// ---------------------------------------------------------------------------
extern "C" void kernel_launch(void* const* d_in, const int* in_sizes, int n_in,
                              void* d_out, int out_size, void* d_ws, size_t ws_size,
                              hipStream_t stream) {
  const float* x   = (const float*)d_in[0];
  const int* eidx  = (const int*)d_in[1];
  const float* W1l = (const float*)d_in[2];
  const float* W1r = (const float*)d_in[3];
  const float* b1  = (const float*)d_in[4];
  const float* g1  = (const float*)d_in[5];
  const float* be1 = (const float*)d_in[6];
  const float* W2l = (const float*)d_in[7];
  const float* W2r = (const float*)d_in[8];
  const float* b2  = (const float*)d_in[9];
  const float* g2  = (const float*)d_in[10];
  const float* be2 = (const float*)d_in[11];
  const float* W3l = (const float*)d_in[12];
  const float* W3r = (const float*)d_in[13];
  const float* b3  = (const float*)d_in[14];
  float* out = (float*)d_out;

  const int N = in_sizes[0] / 128;
  const int E = in_sizes[1] / 2;
  const int* esrc = eidx;
  const int* edst = eidx + E;

  size_t N128 = (size_t)N * 128;
  float* buf0 = (float*)d_ws;
  float* buf1 = buf0 + N128;
  float* sums = buf1 + N128;
  float* scsh = sums + 256;
  int* ideg   = (int*)(scsh + 256);
  int* istart = ideg + N;
  int* ifill  = istart + N;
  int* icnt   = ifill + N;
  int* icol   = icnt + 4;

  // dropout keys: k1,k2 = split(key(42)) under partitionable threefry
  unsigned k1a, k1b, k2a, k2b;
  tf2x32(0u, 42u, 0u, 0u, &k1a, &k1b);
  tf2x32(0u, 42u, 0u, 1u, &k2a, &k2b);

  hipMemsetAsync(ideg, 0, (size_t)N * 4, stream);
  hipMemsetAsync(ifill, 0, (size_t)N * 4, stream);
  hipMemsetAsync(icnt, 0, 16, stream);

  int gE = (E + THREADS - 1) / THREADS;
  int gN = (N + THREADS - 1) / THREADS;
  compute_deg<<<gE, THREADS, 0, stream>>>(edst, ideg, E);
  alloc_starts<<<gN, THREADS, 0, stream>>>(ideg, istart, icnt, N);
  fill_csr<<<gE, THREADS, 0, stream>>>(esrc, edst, istart, ifill, icol, E);

  int gM = (N + 63) / 64;
  int gW = (N + 3) / 4;                 // aggregate128: 4 waves/block
  int half2 = (int)(N128 / 2);
  int gD = (half2 + THREADS - 1) / THREADS;
  int gA16 = (N * 16 + THREADS - 1) / THREADS;

  // ---- Layer 1 ----
  gemm128<<<gM, THREADS, 0, stream>>>(x, W1l, nullptr, buf0, N);
  gemm128<<<gM, THREADS, 0, stream>>>(x, W1r, b1, buf1, N);
  aggregate128<<<gW, THREADS, 0, stream>>>(buf0, buf1, icol, istart, ideg, N);
  hipMemsetAsync(sums, 0, 256 * 4, stream);
  bn_stats<<<200, THREADS, 0, stream>>>(buf1, sums, N);
  bn_finalize<<<1, 128, 0, stream>>>(sums, g1, be1, scsh, (float)N);
  bn_relu_dropout<<<gD, THREADS, 0, stream>>>(buf1, scsh, k1a, k1b, half2);

  // ---- Layer 2 ----
  gemm128<<<gM, THREADS, 0, stream>>>(buf1, W2l, nullptr, buf0, N);
  gemm128<<<gM, THREADS, 0, stream>>>(buf1, W2r, b2, buf1, N);  // in-place safe
  aggregate128<<<gW, THREADS, 0, stream>>>(buf0, buf1, icol, istart, ideg, N);
  hipMemsetAsync(sums, 0, 256 * 4, stream);
  bn_stats<<<200, THREADS, 0, stream>>>(buf1, sums, N);
  bn_finalize<<<1, 128, 0, stream>>>(sums, g2, be2, scsh, (float)N);
  bn_relu_dropout<<<gD, THREADS, 0, stream>>>(buf1, scsh, k2a, k2b, half2);

  // ---- Layer 3 (project to 16 first — fused dual GEMM — then aggregate) ----
  gemm16_dual<<<(N + 15) / 16, THREADS, 0, stream>>>(buf1, W3l, W3r, b3, buf0, out, N);
  aggregate16<<<gA16, THREADS, 0, stream>>>(buf0, out, icol, istart, ideg, N);
}

// Round 3
// 1039.038 us; speedup vs baseline: 1.7148x; 1.0265x over previous
//
#include <hip/hip_runtime.h>
#include <cstdint>
#include <cstddef>

#define THREADS 256

// ---------------------------------------------------------------------------
// JAX threefry2x32 (Random123, 20 rounds) — used for the dropout masks.
// jax_threefry_partitionable=True semantics (verified R1: absmax 0.0156):
// split keys = tf(key,(0,j)); bits[i] = o0^o1 of tf(key,(0,i)).
// ---------------------------------------------------------------------------
__host__ __device__ __forceinline__ void tf2x32(unsigned k0, unsigned k1,
                                                unsigned x0, unsigned x1,
                                                unsigned* o0, unsigned* o1) {
  unsigned ks2 = k0 ^ k1 ^ 0x1BD11BDAu;
  x0 += k0; x1 += k1;
#define TFR(r) { x0 += x1; x1 = (x1 << (r)) | (x1 >> (32 - (r))); x1 ^= x0; }
  TFR(13) TFR(15) TFR(26) TFR(6)   x0 += k1;  x1 += ks2 + 1u;
  TFR(17) TFR(29) TFR(16) TFR(24)  x0 += ks2; x1 += k0 + 2u;
  TFR(13) TFR(15) TFR(26) TFR(6)   x0 += k0;  x1 += k1 + 3u;
  TFR(17) TFR(29) TFR(16) TFR(24)  x0 += k1;  x1 += ks2 + 4u;
  TFR(13) TFR(15) TFR(26) TFR(6)   x0 += ks2; x1 += k0 + 5u;
#undef TFR
  *o0 = x0; *o1 = x1;
}

// fp32 -> bf16 with round-to-nearest-even (matches XLA convert semantics).
__device__ __forceinline__ unsigned f2bf(float f) {
  unsigned b = __float_as_uint(f);
  return (b + 0x7fffu + ((b >> 16) & 1u)) >> 16;
}
__device__ __forceinline__ float bf2f(unsigned hi) {
  return __uint_as_float(hi << 16);
}

// ---------------------------------------------------------------------------
// CSR build (bucket edges by dst). Order within a node is arbitrary (atomic),
// which only perturbs fp32 sum order (~1e-6).
// ---------------------------------------------------------------------------
__global__ __launch_bounds__(THREADS) void compute_deg(const int* __restrict__ dst,
                                                       int* __restrict__ deg, int E) {
  int e = blockIdx.x * THREADS + threadIdx.x;
  if (e < E) atomicAdd(&deg[dst[e]], 1);
}

// Per-block inclusive scan + one global atomic → contiguous per-node segments
// (segment order across blocks arbitrary; aggregation only needs start+deg).
__global__ __launch_bounds__(THREADS) void alloc_starts(const int* __restrict__ deg,
                                                        int* __restrict__ start,
                                                        int* __restrict__ counter, int n) {
  __shared__ int sdata[THREADS];
  __shared__ int sbase;
  int i = blockIdx.x * THREADS + threadIdx.x;
  int d = (i < n) ? deg[i] : 0;
  sdata[threadIdx.x] = d;
  __syncthreads();
  for (int off = 1; off < THREADS; off <<= 1) {
    int v = (threadIdx.x >= off) ? sdata[threadIdx.x - off] : 0;
    __syncthreads();
    sdata[threadIdx.x] += v;
    __syncthreads();
  }
  if (threadIdx.x == THREADS - 1) sbase = atomicAdd(counter, sdata[THREADS - 1]);
  __syncthreads();
  if (i < n) start[i] = sbase + sdata[threadIdx.x] - d;  // exclusive
}

__global__ __launch_bounds__(THREADS) void fill_csr(const int* __restrict__ src,
                                                    const int* __restrict__ dst,
                                                    const int* __restrict__ start,
                                                    int* __restrict__ fill,
                                                    int* __restrict__ colbuf, int E) {
  int e = blockIdx.x * THREADS + threadIdx.x;
  if (e >= E) return;
  int d = dst[e];
  int p = atomicAdd(&fill[d], 1);
  colbuf[start[d] + p] = src[e];
}

// ---------------------------------------------------------------------------
// fp32 GEMM: C[M][128] = A[M][128] @ W[128][128] (+ bias).
// 64-row tile, full 128 cols, BK=32, LDS A stored [k][row].
// OUT_BF16: epilogue packs RNE bf16 pairs (C is then a 256 B/row bf16 matrix).
// Safe for in-place A==C (fp32): block writes only its own rows, post K-loop.
// ---------------------------------------------------------------------------
template <int OUT_BF16>
__global__ __launch_bounds__(THREADS) void gemm128(const float* A,
                                                   const float* __restrict__ W,
                                                   const float* __restrict__ bias,
                                                   void* C, int M) {
  __shared__ __align__(16) float As[32][66];   // [k][row]
  __shared__ __align__(16) float Bs[32][128];  // [k][col]
  int t = threadIdx.x;
  int row0 = blockIdx.x * 64;
  int tx = t & 31;   // col group: cols tx*4..+3
  int ty = t >> 5;   // 0..7 → rows ty*8..+7
  float acc[8][4];
#pragma unroll
  for (int i = 0; i < 8; ++i)
#pragma unroll
    for (int j = 0; j < 4; ++j) acc[i][j] = 0.f;

  for (int k0 = 0; k0 < 128; k0 += 32) {
#pragma unroll
    for (int i = 0; i < 8; ++i) {
      int lin = t + i * THREADS;        // 0..2047
      int r = lin >> 5;
      int k = lin & 31;
      int grow = row0 + r;
      As[k][r] = (grow < M) ? A[(size_t)grow * 128 + k0 + k] : 0.f;
    }
#pragma unroll
    for (int i = 0; i < 4; ++i) {
      int lin = t + i * THREADS;        // 0..1023 float4 ids
      int k = lin >> 5;
      int c = (lin & 31) << 2;
      *(float4*)&Bs[k][c] = *(const float4*)(W + (size_t)(k0 + k) * 128 + c);
    }
    __syncthreads();
#pragma unroll
    for (int k = 0; k < 32; ++k) {
      float4 b = *(const float4*)&Bs[k][tx << 2];
      float a[8];
      *(float2*)&a[0] = *(const float2*)&As[k][ty * 8 + 0];
      *(float2*)&a[2] = *(const float2*)&As[k][ty * 8 + 2];
      *(float2*)&a[4] = *(const float2*)&As[k][ty * 8 + 4];
      *(float2*)&a[6] = *(const float2*)&As[k][ty * 8 + 6];
#pragma unroll
      for (int i = 0; i < 8; ++i) {
        acc[i][0] += a[i] * b.x;
        acc[i][1] += a[i] * b.y;
        acc[i][2] += a[i] * b.z;
        acc[i][3] += a[i] * b.w;
      }
    }
    __syncthreads();
  }
  float4 bb = make_float4(0.f, 0.f, 0.f, 0.f);
  if (bias) bb = *(const float4*)(bias + (tx << 2));
#pragma unroll
  for (int i = 0; i < 8; ++i) {
    int grow = row0 + ty * 8 + i;
    if (grow < M) {
      float o0 = acc[i][0] + bb.x;
      float o1 = acc[i][1] + bb.y;
      float o2 = acc[i][2] + bb.z;
      float o3 = acc[i][3] + bb.w;
      if (OUT_BF16) {
        uint2 p;
        p.x = f2bf(o0) | (f2bf(o1) << 16);
        p.y = f2bf(o2) | (f2bf(o3) << 16);
        *(uint2*)((unsigned short*)C + (size_t)grow * 128 + (tx << 2)) = p;
      } else {
        *(float4*)((float*)C + (size_t)grow * 128 + (tx << 2)) =
            make_float4(o0, o1, o2, o3);
      }
    }
  }
}

// ---------------------------------------------------------------------------
// Fused layer-3 projections: Cl = bf16(A@Wl), Cr = A@Wr + br. Reads A ONCE.
// (R1 post-mortem: split gemm16 hit a 256-VGPR spill cliff; this form holds
// 2 accumulators/thread, unroll capped at 4.)
// ---------------------------------------------------------------------------
__global__ __launch_bounds__(THREADS) void gemm16_dual(const float* __restrict__ A,
                                                       const float* __restrict__ Wl,
                                                       const float* __restrict__ Wr,
                                                       const float* __restrict__ br,
                                                       unsigned short* __restrict__ Cl,
                                                       float* __restrict__ Cr, int M) {
  __shared__ __align__(16) float Wls[128][16];  // [k][col]
  __shared__ __align__(16) float Wrs[128][16];
  __shared__ __align__(16) float As[16][130];   // [row][k], +2 pad
  int t = threadIdx.x;
#pragma unroll
  for (int i = 0; i < 2; ++i) {
    int lin = (t + i * THREADS) << 2;           // float4 id → float offset
    *(float4*)&Wls[0][lin & 2047] = *(const float4*)(Wl + lin);
    *(float4*)&Wrs[0][lin & 2047] = *(const float4*)(Wr + lin);
  }
  int row0 = blockIdx.x * 16;
  int r = t >> 4;     // 0..15 local row
  int c = t & 15;     // col / chunk id
  {
    int grow = row0 + r;
    float4 v0 = make_float4(0.f, 0.f, 0.f, 0.f), v1 = v0;
    if (grow < M) {
      const float* ap = A + (size_t)grow * 128 + c * 8;
      v0 = *(const float4*)(ap);
      v1 = *(const float4*)(ap + 4);
    }
    *(float4*)&As[r][c * 8] = v0;
    *(float4*)&As[r][c * 8 + 4] = v1;
  }
  __syncthreads();
  float accl = 0.f, accr = 0.f;
#pragma unroll 4
  for (int k = 0; k < 128; ++k) {
    float a = As[r][k];                          // broadcast across 16 lanes
    accl += a * Wls[k][c];
    accr += a * Wrs[k][c];
  }
  int grow = row0 + r;
  if (grow < M) {
    Cl[(size_t)grow * 16 + c] = (unsigned short)f2bf(accl);
    Cr[(size_t)grow * 16 + c] = accr + br[c];
  }
}

// ---------------------------------------------------------------------------
// Z[n] += agg(Ybf16)[n] / max(deg,1): one wave per node, 1 uint (2 bf16
// cols) per lane → 256 B per gathered row (was 512 B fp32 — the R2 top-5
// fetch-bound hotspot, 403 MB HBM fetch per dispatch).
// ---------------------------------------------------------------------------
__global__ __launch_bounds__(THREADS) void aggregate128_bf16(
    const unsigned short* __restrict__ Y, float* __restrict__ Z,
    const int* __restrict__ colbuf, const int* __restrict__ start,
    const int* __restrict__ deg, int nnodes) {
  int w = (blockIdx.x * THREADS + threadIdx.x) >> 6;  // node = global wave id
  int lane = threadIdx.x & 63;
  if (w >= nnodes) return;
  int s0 = start[w];
  int dg = deg[w];
  float2 acc = {0.f, 0.f};
  int s_next = (dg > 0) ? colbuf[s0] : 0;
  for (int i = 0; i < dg; ++i) {
    int s = s_next;
    if (i + 1 < dg) s_next = colbuf[s0 + i + 1];   // prefetch next edge id
    unsigned u = *(const unsigned*)(Y + (size_t)s * 128 + (lane << 1));
    acc.x += __uint_as_float(u << 16);             // low bf16 → col 2*lane
    acc.y += __uint_as_float(u & 0xffff0000u);     // high bf16 → col 2*lane+1
  }
  float sc = 1.0f / fmaxf((float)dg, 1.0f);
  size_t off = (size_t)w * 128 + (lane << 1);
  float2 z = *(const float2*)(Z + off);
  z.x += acc.x * sc;
  z.y += acc.y * sc;
  *(float2*)(Z + off) = z;
}

// Out[n][c] += agg(Ybf16)[n][c] / max(deg,1): 16 threads per node.
__global__ __launch_bounds__(THREADS) void aggregate16_bf16(
    const unsigned short* __restrict__ Y, float* __restrict__ Out,
    const int* __restrict__ colbuf, const int* __restrict__ start,
    const int* __restrict__ deg, int nnodes) {
  int gid = blockIdx.x * THREADS + threadIdx.x;
  int n = gid >> 4;
  int c = gid & 15;
  if (n >= nnodes) return;
  int s0 = start[n];
  int dg = deg[n];
  float acc = 0.f;
  for (int i = 0; i < dg; ++i) {
    int s = colbuf[s0 + i];
    acc += bf2f(Y[(size_t)s * 16 + c]);
  }
  float sc = 1.0f / fmaxf((float)dg, 1.0f);
  Out[(size_t)n * 16 + c] += acc * sc;
}

// ---------------------------------------------------------------------------
// BN: column sums/sumsq → scale/shift → fused affine+ReLU+dropout (in place).
// ---------------------------------------------------------------------------
__global__ __launch_bounds__(THREADS) void bn_stats(const float* __restrict__ H,
                                                    float* __restrict__ sums, int n) {
  int col = threadIdx.x & 127;
  int half = threadIdx.x >> 7;  // 0/1
  float s = 0.f, sq = 0.f;
  for (int r = blockIdx.x * 2 + half; r < n; r += gridDim.x * 2) {
    float v = H[(size_t)r * 128 + col];
    s += v;
    sq += v * v;
  }
  __shared__ float ls[THREADS], lq[THREADS];
  ls[threadIdx.x] = s;
  lq[threadIdx.x] = sq;
  __syncthreads();
  if (half == 0) {
    s += ls[col + 128];
    sq += lq[col + 128];
    atomicAdd(&sums[col], s);
    atomicAdd(&sums[128 + col], sq);
  }
}

__global__ void bn_finalize(const float* __restrict__ sums,
                            const float* __restrict__ g,
                            const float* __restrict__ be,
                            float* __restrict__ scsh, float n) {
  int c = threadIdx.x;  // 128 threads
  float mu = sums[c] / n;
  float var = sums[128 + c] / n - mu * mu;
  float inv = rsqrtf(var + 1e-5f);
  float sc = g[c] * inv;
  scsh[c] = sc;
  scsh[128 + c] = be[c] - mu * sc;
}

// keep[i] = msb(o0^o1 of tf(key,(0,i))) == 0  (uniform<0.5, partitionable).
// H[i] = keep ? 2*relu(H[i]*scale+shift) : 0. Two elements (float2) / thread.
__global__ __launch_bounds__(THREADS) void bn_relu_dropout(float* __restrict__ H,
                                                           const float* __restrict__ scsh,
                                                           unsigned k0, unsigned k1,
                                                           int count2) {
  int j = blockIdx.x * THREADS + threadIdx.x;  // element pair id
  if (j >= count2) return;
  unsigned i0 = (unsigned)j << 1;
  unsigned a0, a1, b0, b1;
  tf2x32(k0, k1, 0u, i0, &a0, &a1);
  tf2x32(k0, k1, 0u, i0 + 1u, &b0, &b1);
  int col = (int)(i0 & 127u);  // even
  float2 v = *(float2*)(H + i0);
  float s0 = scsh[col], sh0 = scsh[128 + col];
  float s1 = scsh[col + 1], sh1 = scsh[129 + col];
  v.x = fmaxf(v.x * s0 + sh0, 0.f);
  v.y = fmaxf(v.y * s1 + sh1, 0.f);
  v.x = ((a0 ^ a1) >> 31) ? 0.f : 2.f * v.x;
  v.y = ((b0 ^ b1) >> 31) ? 0.f : 2.f * v.y;
  *(float2*)(H + i0) = v;
}

// ---------------------------------------------------------------------------
// Launch: CSR once; per layer GEMM(Wl)→buf0 (bf16), GEMM(Wr)+b→h (fp32),
// bf16 gather-agg into h, BN stats/finalize, fused BN+ReLU+dropout.
// Layer-3 projects to 16 (fused dual GEMM) then aggregates bf16.
// ---------------------------------------------------------------------------
extern "C" void kernel_launch(void* const* d_in, const int* in_sizes, int n_in,
                              void* d_out, int out_size, void* d_ws, size_t ws_size,
                              hipStream_t stream) {
  const float* x   = (const float*)d_in[0];
  const int* eidx  = (const int*)d_in[1];
  const float* W1l = (const float*)d_in[2];
  const float* W1r = (const float*)d_in[3];
  const float* b1  = (const float*)d_in[4];
  const float* g1  = (const float*)d_in[5];
  const float* be1 = (const float*)d_in[6];
  const float* W2l = (const float*)d_in[7];
  const float* W2r = (const float*)d_in[8];
  const float* b2  = (const float*)d_in[9];
  const float* g2  = (const float*)d_in[10];
  const float* be2 = (const float*)d_in[11];
  const float* W3l = (const float*)d_in[12];
  const float* W3r = (const float*)d_in[13];
  const float* b3  = (const float*)d_in[14];
  float* out = (float*)d_out;

  const int N = in_sizes[0] / 128;
  const int E = in_sizes[1] / 2;
  const int* esrc = eidx;
  const int* edst = eidx + E;

  size_t N128 = (size_t)N * 128;
  float* buf0 = (float*)d_ws;                 // holds bf16 N×128 (uses half)
  float* buf1 = buf0 + N128;
  float* sums = buf1 + N128;
  float* scsh = sums + 256;
  int* ideg   = (int*)(scsh + 256);
  int* istart = ideg + N;
  int* ifill  = istart + N;
  int* icnt   = ifill + N;
  int* icol   = icnt + 4;
  unsigned short* buf0h = (unsigned short*)buf0;

  // dropout keys: k1,k2 = split(key(42)) under partitionable threefry
  unsigned k1a, k1b, k2a, k2b;
  tf2x32(0u, 42u, 0u, 0u, &k1a, &k1b);
  tf2x32(0u, 42u, 0u, 1u, &k2a, &k2b);

  hipMemsetAsync(ideg, 0, (size_t)N * 4, stream);
  hipMemsetAsync(ifill, 0, (size_t)N * 4, stream);
  hipMemsetAsync(icnt, 0, 16, stream);

  int gE = (E + THREADS - 1) / THREADS;
  int gN = (N + THREADS - 1) / THREADS;
  compute_deg<<<gE, THREADS, 0, stream>>>(edst, ideg, E);
  alloc_starts<<<gN, THREADS, 0, stream>>>(ideg, istart, icnt, N);
  fill_csr<<<gE, THREADS, 0, stream>>>(esrc, edst, istart, ifill, icol, E);

  int gM = (N + 63) / 64;
  int gW = (N + 3) / 4;                 // aggregate128: 4 waves/block
  int half2 = (int)(N128 / 2);
  int gD = (half2 + THREADS - 1) / THREADS;
  int gA16 = (N * 16 + THREADS - 1) / THREADS;

  // ---- Layer 1 ----
  gemm128<1><<<gM, THREADS, 0, stream>>>(x, W1l, nullptr, buf0, N);
  gemm128<0><<<gM, THREADS, 0, stream>>>(x, W1r, b1, buf1, N);
  aggregate128_bf16<<<gW, THREADS, 0, stream>>>(buf0h, buf1, icol, istart, ideg, N);
  hipMemsetAsync(sums, 0, 256 * 4, stream);
  bn_stats<<<200, THREADS, 0, stream>>>(buf1, sums, N);
  bn_finalize<<<1, 128, 0, stream>>>(sums, g1, be1, scsh, (float)N);
  bn_relu_dropout<<<gD, THREADS, 0, stream>>>(buf1, scsh, k1a, k1b, half2);

  // ---- Layer 2 ----
  gemm128<1><<<gM, THREADS, 0, stream>>>(buf1, W2l, nullptr, buf0, N);
  gemm128<0><<<gM, THREADS, 0, stream>>>(buf1, W2r, b2, buf1, N);  // in-place safe
  aggregate128_bf16<<<gW, THREADS, 0, stream>>>(buf0h, buf1, icol, istart, ideg, N);
  hipMemsetAsync(sums, 0, 256 * 4, stream);
  bn_stats<<<200, THREADS, 0, stream>>>(buf1, sums, N);
  bn_finalize<<<1, 128, 0, stream>>>(sums, g2, be2, scsh, (float)N);
  bn_relu_dropout<<<gD, THREADS, 0, stream>>>(buf1, scsh, k2a, k2b, half2);

  // ---- Layer 3 (fused dual 16-wide GEMM, then bf16 aggregate) ----
  gemm16_dual<<<(N + 15) / 16, THREADS, 0, stream>>>(buf1, W3l, W3r, b3, buf0h, out, N);
  aggregate16_bf16<<<gA16, THREADS, 0, stream>>>(buf0h, out, icol, istart, ideg, N);
}

// Round 4
// 918.612 us; speedup vs baseline: 1.9396x; 1.1311x over previous
//
#include <hip/hip_runtime.h>
#include <cstdint>
#include <cstddef>

#define THREADS 256

// ---------------------------------------------------------------------------
// JAX threefry2x32 (Random123, 20 rounds) — used for the dropout masks.
// jax_threefry_partitionable=True semantics (verified R1: absmax 0.0156):
// split keys = tf(key,(0,j)); bits[i] = o0^o1 of tf(key,(0,i)).
// ---------------------------------------------------------------------------
__host__ __device__ __forceinline__ void tf2x32(unsigned k0, unsigned k1,
                                                unsigned x0, unsigned x1,
                                                unsigned* o0, unsigned* o1) {
  unsigned ks2 = k0 ^ k1 ^ 0x1BD11BDAu;
  x0 += k0; x1 += k1;
#define TFR(r) { x0 += x1; x1 = (x1 << (r)) | (x1 >> (32 - (r))); x1 ^= x0; }
  TFR(13) TFR(15) TFR(26) TFR(6)   x0 += k1;  x1 += ks2 + 1u;
  TFR(17) TFR(29) TFR(16) TFR(24)  x0 += ks2; x1 += k0 + 2u;
  TFR(13) TFR(15) TFR(26) TFR(6)   x0 += k0;  x1 += k1 + 3u;
  TFR(17) TFR(29) TFR(16) TFR(24)  x0 += k1;  x1 += ks2 + 4u;
  TFR(13) TFR(15) TFR(26) TFR(6)   x0 += ks2; x1 += k0 + 5u;
#undef TFR
  *o0 = x0; *o1 = x1;
}

// fp32 -> bf16 with round-to-nearest-even (matches XLA convert semantics).
__device__ __forceinline__ unsigned f2bf(float f) {
  unsigned b = __float_as_uint(f);
  return (b + 0x7fffu + ((b >> 16) & 1u)) >> 16;
}
__device__ __forceinline__ float bf2f(unsigned hi) {
  return __uint_as_float(hi << 16);
}

// ---------------------------------------------------------------------------
// CSR build. R3 post-mortem: atomic-order segment allocation gave randomly
// scattered segments → fill stores hit all 8 non-coherent XCD L2s →
// WRITE_SIZE 107 MB for a 6.4 MB colbuf (full 64 B line per 4 B store).
// Fix: deterministic monotone starts (3-kernel prefix scan) + XCD-range-
// partitioned fill: group g = blockIdx&7 handles dst range g → its ~800 KB
// colbuf window stays in ONE XCD's L2 and lines write back once.
// ---------------------------------------------------------------------------
__global__ __launch_bounds__(THREADS) void compute_deg(const int* __restrict__ dst,
                                                       int* __restrict__ deg, int E) {
  int e = blockIdx.x * THREADS + threadIdx.x;
  if (e < E) atomicAdd(&deg[dst[e]], 1);
}

// scan1: per-block local exclusive scan of deg into start; block total → blksum.
__global__ __launch_bounds__(THREADS) void scan1_local(const int* __restrict__ deg,
                                                       int* __restrict__ start,
                                                       int* __restrict__ blksum, int n) {
  __shared__ int sdata[THREADS];
  int i = blockIdx.x * THREADS + threadIdx.x;
  int d = (i < n) ? deg[i] : 0;
  sdata[threadIdx.x] = d;
  __syncthreads();
  for (int off = 1; off < THREADS; off <<= 1) {
    int v = (threadIdx.x >= off) ? sdata[threadIdx.x - off] : 0;
    __syncthreads();
    sdata[threadIdx.x] += v;
    __syncthreads();
  }
  if (i < n) start[i] = sdata[threadIdx.x] - d;  // local exclusive
  if (threadIdx.x == THREADS - 1) blksum[blockIdx.x] = sdata[THREADS - 1];
}

// scan2: ONE block (512 thr) exclusive-scans the <=512 block sums.
__global__ __launch_bounds__(512) void scan2_blocks(const int* __restrict__ blksum,
                                                    int* __restrict__ blkbase, int nb) {
  __shared__ int sdata[512];
  int t = threadIdx.x;
  int v = (t < nb) ? blksum[t] : 0;
  sdata[t] = v;
  __syncthreads();
  for (int off = 1; off < 512; off <<= 1) {
    int u = (t >= off) ? sdata[t - off] : 0;
    __syncthreads();
    sdata[t] += u;
    __syncthreads();
  }
  if (t < nb) blkbase[t] = sdata[t] - v;  // exclusive
}

// scan3: start[i] += blkbase[block]  → globally monotone exclusive starts.
__global__ __launch_bounds__(THREADS) void scan3_add(int* __restrict__ start,
                                                     const int* __restrict__ blkbase,
                                                     int n) {
  int i = blockIdx.x * THREADS + threadIdx.x;
  if (i < n) start[i] += blkbase[blockIdx.x];
}

// XCD-range-partitioned fill. grid = 8 groups x nchunk blocks; group g
// (blockIdx&7 → XCD g under round-robin dispatch) processes only dst in
// [g*rngw, (g+1)*rngw). dst/src reads stay coalesced (8x re-read, LLC-served);
// colbuf writes become XCD-local and line-dense.
__global__ __launch_bounds__(THREADS) void fill_csr_xcd(const int* __restrict__ src,
                                                        const int* __restrict__ dst,
                                                        const int* __restrict__ start,
                                                        int* __restrict__ fill,
                                                        int* __restrict__ colbuf,
                                                        int E, int rngw) {
  int g = blockIdx.x & 7;
  int chunk = blockIdx.x >> 3;
  int nchunk = gridDim.x >> 3;
  int lo = g * rngw, hi = lo + rngw;
  int stride = nchunk * THREADS;
  for (int e = chunk * THREADS + threadIdx.x; e < E; e += stride) {
    int d = dst[e];
    if (d >= lo && d < hi) {
      int p = atomicAdd(&fill[d], 1);
      colbuf[start[d] + p] = src[e];
    }
  }
}

// ---------------------------------------------------------------------------
// fp32 GEMM: C[M][128] = A[M][128] @ W[128][128] (+ bias).
// 64-row tile, full 128 cols, BK=32, LDS A stored [k][row].
// OUT_BF16: epilogue packs RNE bf16 pairs (C is then a 256 B/row bf16 matrix).
// Safe for in-place A==C (fp32): block writes only its own rows, post K-loop.
// ---------------------------------------------------------------------------
template <int OUT_BF16>
__global__ __launch_bounds__(THREADS) void gemm128(const float* A,
                                                   const float* __restrict__ W,
                                                   const float* __restrict__ bias,
                                                   void* C, int M) {
  __shared__ __align__(16) float As[32][66];   // [k][row]
  __shared__ __align__(16) float Bs[32][128];  // [k][col]
  int t = threadIdx.x;
  int row0 = blockIdx.x * 64;
  int tx = t & 31;   // col group: cols tx*4..+3
  int ty = t >> 5;   // 0..7 → rows ty*8..+7
  float acc[8][4];
#pragma unroll
  for (int i = 0; i < 8; ++i)
#pragma unroll
    for (int j = 0; j < 4; ++j) acc[i][j] = 0.f;

  for (int k0 = 0; k0 < 128; k0 += 32) {
#pragma unroll
    for (int i = 0; i < 8; ++i) {
      int lin = t + i * THREADS;        // 0..2047
      int r = lin >> 5;
      int k = lin & 31;
      int grow = row0 + r;
      As[k][r] = (grow < M) ? A[(size_t)grow * 128 + k0 + k] : 0.f;
    }
#pragma unroll
    for (int i = 0; i < 4; ++i) {
      int lin = t + i * THREADS;        // 0..1023 float4 ids
      int k = lin >> 5;
      int c = (lin & 31) << 2;
      *(float4*)&Bs[k][c] = *(const float4*)(W + (size_t)(k0 + k) * 128 + c);
    }
    __syncthreads();
#pragma unroll
    for (int k = 0; k < 32; ++k) {
      float4 b = *(const float4*)&Bs[k][tx << 2];
      float a[8];
      *(float2*)&a[0] = *(const float2*)&As[k][ty * 8 + 0];
      *(float2*)&a[2] = *(const float2*)&As[k][ty * 8 + 2];
      *(float2*)&a[4] = *(const float2*)&As[k][ty * 8 + 4];
      *(float2*)&a[6] = *(const float2*)&As[k][ty * 8 + 6];
#pragma unroll
      for (int i = 0; i < 8; ++i) {
        acc[i][0] += a[i] * b.x;
        acc[i][1] += a[i] * b.y;
        acc[i][2] += a[i] * b.z;
        acc[i][3] += a[i] * b.w;
      }
    }
    __syncthreads();
  }
  float4 bb = make_float4(0.f, 0.f, 0.f, 0.f);
  if (bias) bb = *(const float4*)(bias + (tx << 2));
#pragma unroll
  for (int i = 0; i < 8; ++i) {
    int grow = row0 + ty * 8 + i;
    if (grow < M) {
      float o0 = acc[i][0] + bb.x;
      float o1 = acc[i][1] + bb.y;
      float o2 = acc[i][2] + bb.z;
      float o3 = acc[i][3] + bb.w;
      if (OUT_BF16) {
        uint2 p;
        p.x = f2bf(o0) | (f2bf(o1) << 16);
        p.y = f2bf(o2) | (f2bf(o3) << 16);
        *(uint2*)((unsigned short*)C + (size_t)grow * 128 + (tx << 2)) = p;
      } else {
        *(float4*)((float*)C + (size_t)grow * 128 + (tx << 2)) =
            make_float4(o0, o1, o2, o3);
      }
    }
  }
}

// ---------------------------------------------------------------------------
// Fused layer-3 projections: Cl = bf16(A@Wl), Cr = A@Wr + br. Reads A ONCE.
// (R1 post-mortem: split gemm16 hit a 256-VGPR spill cliff; this form holds
// 2 accumulators/thread, unroll capped at 4.)
// ---------------------------------------------------------------------------
__global__ __launch_bounds__(THREADS) void gemm16_dual(const float* __restrict__ A,
                                                       const float* __restrict__ Wl,
                                                       const float* __restrict__ Wr,
                                                       const float* __restrict__ br,
                                                       unsigned short* __restrict__ Cl,
                                                       float* __restrict__ Cr, int M) {
  __shared__ __align__(16) float Wls[128][16];  // [k][col]
  __shared__ __align__(16) float Wrs[128][16];
  __shared__ __align__(16) float As[16][130];   // [row][k], +2 pad
  int t = threadIdx.x;
#pragma unroll
  for (int i = 0; i < 2; ++i) {
    int lin = (t + i * THREADS) << 2;           // float4 id → float offset
    *(float4*)&Wls[0][lin & 2047] = *(const float4*)(Wl + lin);
    *(float4*)&Wrs[0][lin & 2047] = *(const float4*)(Wr + lin);
  }
  int row0 = blockIdx.x * 16;
  int r = t >> 4;     // 0..15 local row
  int c = t & 15;     // col / chunk id
  {
    int grow = row0 + r;
    float4 v0 = make_float4(0.f, 0.f, 0.f, 0.f), v1 = v0;
    if (grow < M) {
      const float* ap = A + (size_t)grow * 128 + c * 8;
      v0 = *(const float4*)(ap);
      v1 = *(const float4*)(ap + 4);
    }
    *(float4*)&As[r][c * 8] = v0;
    *(float4*)&As[r][c * 8 + 4] = v1;
  }
  __syncthreads();
  float accl = 0.f, accr = 0.f;
#pragma unroll 4
  for (int k = 0; k < 128; ++k) {
    float a = As[r][k];                          // broadcast across 16 lanes
    accl += a * Wls[k][c];
    accr += a * Wrs[k][c];
  }
  int grow = row0 + r;
  if (grow < M) {
    Cl[(size_t)grow * 16 + c] = (unsigned short)f2bf(accl);
    Cr[(size_t)grow * 16 + c] = accr + br[c];
  }
}

// ---------------------------------------------------------------------------
// Z[n] += agg(Ybf16)[n] / max(deg,1): one wave per node, uint (2 bf16 cols)
// per lane. R3 post-mortem: latency×TLP bound (1 row gather in flight/wave →
// waves/latency ≈ 10 G rows/s ≈ observed). Unroll edges ×4 → 4 independent
// gathers in flight per wave.
// ---------------------------------------------------------------------------
__global__ __launch_bounds__(THREADS) void aggregate128_bf16(
    const unsigned short* __restrict__ Y, float* __restrict__ Z,
    const int* __restrict__ colbuf, const int* __restrict__ start,
    const int* __restrict__ deg, int nnodes) {
  int w = (blockIdx.x * THREADS + threadIdx.x) >> 6;  // node = global wave id
  int lane = threadIdx.x & 63;
  if (w >= nnodes) return;
  const int* cb = colbuf + start[w];
  int dg = deg[w];
  const unsigned short* yp = Y + (lane << 1);
  float ax = 0.f, ay = 0.f;
  int i = 0;
  for (; i + 4 <= dg; i += 4) {
    int e0 = cb[i], e1 = cb[i + 1], e2 = cb[i + 2], e3 = cb[i + 3];
    unsigned u0 = *(const unsigned*)(yp + (size_t)e0 * 128);
    unsigned u1 = *(const unsigned*)(yp + (size_t)e1 * 128);
    unsigned u2 = *(const unsigned*)(yp + (size_t)e2 * 128);
    unsigned u3 = *(const unsigned*)(yp + (size_t)e3 * 128);
    ax += __uint_as_float(u0 << 16);
    ay += __uint_as_float(u0 & 0xffff0000u);
    ax += __uint_as_float(u1 << 16);
    ay += __uint_as_float(u1 & 0xffff0000u);
    ax += __uint_as_float(u2 << 16);
    ay += __uint_as_float(u2 & 0xffff0000u);
    ax += __uint_as_float(u3 << 16);
    ay += __uint_as_float(u3 & 0xffff0000u);
  }
  for (; i < dg; ++i) {
    unsigned u = *(const unsigned*)(yp + (size_t)cb[i] * 128);
    ax += __uint_as_float(u << 16);
    ay += __uint_as_float(u & 0xffff0000u);
  }
  float sc = 1.0f / fmaxf((float)dg, 1.0f);
  size_t off = (size_t)w * 128 + (lane << 1);
  float2 z = *(const float2*)(Z + off);
  z.x += ax * sc;
  z.y += ay * sc;
  *(float2*)(Z + off) = z;
}

// Out[n] += agg(Y16bf16)[n] / max(deg,1): 8 threads/node, uint (2 cols) each,
// edges unrolled ×4 for MLP.
__global__ __launch_bounds__(THREADS) void aggregate16_bf16(
    const unsigned short* __restrict__ Y, float* __restrict__ Out,
    const int* __restrict__ colbuf, const int* __restrict__ start,
    const int* __restrict__ deg, int nnodes) {
  int gid = blockIdx.x * THREADS + threadIdx.x;
  int n = gid >> 3;
  int cp = gid & 7;             // col pair: cols 2cp, 2cp+1
  if (n >= nnodes) return;
  const int* cb = colbuf + start[n];
  int dg = deg[n];
  const unsigned short* yp = Y + (cp << 1);
  float ax = 0.f, ay = 0.f;
  int i = 0;
  for (; i + 4 <= dg; i += 4) {
    int e0 = cb[i], e1 = cb[i + 1], e2 = cb[i + 2], e3 = cb[i + 3];
    unsigned u0 = *(const unsigned*)(yp + (size_t)e0 * 16);
    unsigned u1 = *(const unsigned*)(yp + (size_t)e1 * 16);
    unsigned u2 = *(const unsigned*)(yp + (size_t)e2 * 16);
    unsigned u3 = *(const unsigned*)(yp + (size_t)e3 * 16);
    ax += __uint_as_float(u0 << 16);
    ay += __uint_as_float(u0 & 0xffff0000u);
    ax += __uint_as_float(u1 << 16);
    ay += __uint_as_float(u1 & 0xffff0000u);
    ax += __uint_as_float(u2 << 16);
    ay += __uint_as_float(u2 & 0xffff0000u);
    ax += __uint_as_float(u3 << 16);
    ay += __uint_as_float(u3 & 0xffff0000u);
  }
  for (; i < dg; ++i) {
    unsigned u = *(const unsigned*)(yp + (size_t)cb[i] * 16);
    ax += __uint_as_float(u << 16);
    ay += __uint_as_float(u & 0xffff0000u);
  }
  float sc = 1.0f / fmaxf((float)dg, 1.0f);
  size_t off = (size_t)n * 16 + (cp << 1);
  float2 o = *(const float2*)(Out + off);
  o.x += ax * sc;
  o.y += ay * sc;
  *(float2*)(Out + off) = o;
}

// ---------------------------------------------------------------------------
// BN: column sums/sumsq → scale/shift → fused affine+ReLU+dropout (in place).
// ---------------------------------------------------------------------------
__global__ __launch_bounds__(THREADS) void bn_stats(const float* __restrict__ H,
                                                    float* __restrict__ sums, int n) {
  int col = threadIdx.x & 127;
  int half = threadIdx.x >> 7;  // 0/1
  float s = 0.f, sq = 0.f;
  for (int r = blockIdx.x * 2 + half; r < n; r += gridDim.x * 2) {
    float v = H[(size_t)r * 128 + col];
    s += v;
    sq += v * v;
  }
  __shared__ float ls[THREADS], lq[THREADS];
  ls[threadIdx.x] = s;
  lq[threadIdx.x] = sq;
  __syncthreads();
  if (half == 0) {
    s += ls[col + 128];
    sq += lq[col + 128];
    atomicAdd(&sums[col], s);
    atomicAdd(&sums[128 + col], sq);
  }
}

__global__ void bn_finalize(const float* __restrict__ sums,
                            const float* __restrict__ g,
                            const float* __restrict__ be,
                            float* __restrict__ scsh, float n) {
  int c = threadIdx.x;  // 128 threads
  float mu = sums[c] / n;
  float var = sums[128 + c] / n - mu * mu;
  float inv = rsqrtf(var + 1e-5f);
  float sc = g[c] * inv;
  scsh[c] = sc;
  scsh[128 + c] = be[c] - mu * sc;
}

// keep[i] = msb(o0^o1 of tf(key,(0,i))) == 0  (uniform<0.5, partitionable).
// H[i] = keep ? 2*relu(H[i]*scale+shift) : 0. Two elements (float2) / thread.
__global__ __launch_bounds__(THREADS) void bn_relu_dropout(float* __restrict__ H,
                                                           const float* __restrict__ scsh,
                                                           unsigned k0, unsigned k1,
                                                           int count2) {
  int j = blockIdx.x * THREADS + threadIdx.x;  // element pair id
  if (j >= count2) return;
  unsigned i0 = (unsigned)j << 1;
  unsigned a0, a1, b0, b1;
  tf2x32(k0, k1, 0u, i0, &a0, &a1);
  tf2x32(k0, k1, 0u, i0 + 1u, &b0, &b1);
  int col = (int)(i0 & 127u);  // even
  float2 v = *(float2*)(H + i0);
  float s0 = scsh[col], sh0 = scsh[128 + col];
  float s1 = scsh[col + 1], sh1 = scsh[129 + col];
  v.x = fmaxf(v.x * s0 + sh0, 0.f);
  v.y = fmaxf(v.y * s1 + sh1, 0.f);
  v.x = ((a0 ^ a1) >> 31) ? 0.f : 2.f * v.x;
  v.y = ((b0 ^ b1) >> 31) ? 0.f : 2.f * v.y;
  *(float2*)(H + i0) = v;
}

// ---------------------------------------------------------------------------
// Launch: CSR (deg → 3-kernel scan → XCD-partitioned fill); per layer
// GEMM(Wl)→buf0(bf16), GEMM(Wr)+b→h(fp32), unrolled bf16 gather-agg into h,
// BN stats/finalize, fused BN+ReLU+dropout. Layer-3: fused dual 16-wide GEMM
// then bf16 aggregate.
// ---------------------------------------------------------------------------
extern "C" void kernel_launch(void* const* d_in, const int* in_sizes, int n_in,
                              void* d_out, int out_size, void* d_ws, size_t ws_size,
                              hipStream_t stream) {
  const float* x   = (const float*)d_in[0];
  const int* eidx  = (const int*)d_in[1];
  const float* W1l = (const float*)d_in[2];
  const float* W1r = (const float*)d_in[3];
  const float* b1  = (const float*)d_in[4];
  const float* g1  = (const float*)d_in[5];
  const float* be1 = (const float*)d_in[6];
  const float* W2l = (const float*)d_in[7];
  const float* W2r = (const float*)d_in[8];
  const float* b2  = (const float*)d_in[9];
  const float* g2  = (const float*)d_in[10];
  const float* be2 = (const float*)d_in[11];
  const float* W3l = (const float*)d_in[12];
  const float* W3r = (const float*)d_in[13];
  const float* b3  = (const float*)d_in[14];
  float* out = (float*)d_out;

  const int N = in_sizes[0] / 128;
  const int E = in_sizes[1] / 2;
  const int* esrc = eidx;
  const int* edst = eidx + E;

  size_t N128 = (size_t)N * 128;
  float* buf0 = (float*)d_ws;                 // holds bf16 N×128 (uses half)
  float* buf1 = buf0 + N128;
  float* sums = buf1 + N128;
  float* scsh = sums + 256;
  int* ideg   = (int*)(scsh + 256);
  int* istart = ideg + N;
  int* ifill  = istart + N;
  int* iblksum = ifill + N;                   // 512
  int* iblkbase = iblksum + 512;              // 512
  int* icol   = iblkbase + 512;
  unsigned short* buf0h = (unsigned short*)buf0;

  // dropout keys: k1,k2 = split(key(42)) under partitionable threefry
  unsigned k1a, k1b, k2a, k2b;
  tf2x32(0u, 42u, 0u, 0u, &k1a, &k1b);
  tf2x32(0u, 42u, 0u, 1u, &k2a, &k2b);

  hipMemsetAsync(ideg, 0, (size_t)N * 4, stream);
  hipMemsetAsync(ifill, 0, (size_t)N * 4, stream);

  int gE = (E + THREADS - 1) / THREADS;
  int gN = (N + THREADS - 1) / THREADS;      // == #scan blocks, must be <=512
  compute_deg<<<gE, THREADS, 0, stream>>>(edst, ideg, E);
  scan1_local<<<gN, THREADS, 0, stream>>>(ideg, istart, iblksum, N);
  scan2_blocks<<<1, 512, 0, stream>>>(iblksum, iblkbase, gN);
  scan3_add<<<gN, THREADS, 0, stream>>>(istart, iblkbase, N);
  int rngw = (N + 7) / 8;
  fill_csr_xcd<<<512, THREADS, 0, stream>>>(esrc, edst, istart, ifill, icol, E, rngw);

  int gM = (N + 63) / 64;
  int gW = (N + 3) / 4;                 // aggregate128: 4 waves/block
  int half2 = (int)(N128 / 2);
  int gD = (half2 + THREADS - 1) / THREADS;
  int gA16 = (N * 8 + THREADS - 1) / THREADS;

  // ---- Layer 1 ----
  gemm128<1><<<gM, THREADS, 0, stream>>>(x, W1l, nullptr, buf0, N);
  gemm128<0><<<gM, THREADS, 0, stream>>>(x, W1r, b1, buf1, N);
  aggregate128_bf16<<<gW, THREADS, 0, stream>>>(buf0h, buf1, icol, istart, ideg, N);
  hipMemsetAsync(sums, 0, 256 * 4, stream);
  bn_stats<<<200, THREADS, 0, stream>>>(buf1, sums, N);
  bn_finalize<<<1, 128, 0, stream>>>(sums, g1, be1, scsh, (float)N);
  bn_relu_dropout<<<gD, THREADS, 0, stream>>>(buf1, scsh, k1a, k1b, half2);

  // ---- Layer 2 ----
  gemm128<1><<<gM, THREADS, 0, stream>>>(buf1, W2l, nullptr, buf0, N);
  gemm128<0><<<gM, THREADS, 0, stream>>>(buf1, W2r, b2, buf1, N);  // in-place safe
  aggregate128_bf16<<<gW, THREADS, 0, stream>>>(buf0h, buf1, icol, istart, ideg, N);
  hipMemsetAsync(sums, 0, 256 * 4, stream);
  bn_stats<<<200, THREADS, 0, stream>>>(buf1, sums, N);
  bn_finalize<<<1, 128, 0, stream>>>(sums, g2, be2, scsh, (float)N);
  bn_relu_dropout<<<gD, THREADS, 0, stream>>>(buf1, scsh, k2a, k2b, half2);

  // ---- Layer 3 (fused dual 16-wide GEMM, then bf16 aggregate) ----
  gemm16_dual<<<(N + 15) / 16, THREADS, 0, stream>>>(buf1, W3l, W3r, b3, buf0h, out, N);
  aggregate16_bf16<<<gA16, THREADS, 0, stream>>>(buf0h, out, icol, istart, ideg, N);
}

// Round 5
// 796.990 us; speedup vs baseline: 2.2356x; 1.1526x over previous
//
#include <hip/hip_runtime.h>
#include <cstdint>
#include <cstddef>

#define THREADS 256

typedef __attribute__((ext_vector_type(8))) short bf16x8;
typedef __attribute__((ext_vector_type(4))) float f32x4;

// ---------------------------------------------------------------------------
// JAX threefry2x32 (Random123, 20 rounds) — used for the dropout masks.
// jax_threefry_partitionable=True semantics (verified R1: absmax 0.0156):
// split keys = tf(key,(0,j)); bits[i] = o0^o1 of tf(key,(0,i)).
// ---------------------------------------------------------------------------
__host__ __device__ __forceinline__ void tf2x32(unsigned k0, unsigned k1,
                                                unsigned x0, unsigned x1,
                                                unsigned* o0, unsigned* o1) {
  unsigned ks2 = k0 ^ k1 ^ 0x1BD11BDAu;
  x0 += k0; x1 += k1;
#define TFR(r) { x0 += x1; x1 = (x1 << (r)) | (x1 >> (32 - (r))); x1 ^= x0; }
  TFR(13) TFR(15) TFR(26) TFR(6)   x0 += k1;  x1 += ks2 + 1u;
  TFR(17) TFR(29) TFR(16) TFR(24)  x0 += ks2; x1 += k0 + 2u;
  TFR(13) TFR(15) TFR(26) TFR(6)   x0 += k0;  x1 += k1 + 3u;
  TFR(17) TFR(29) TFR(16) TFR(24)  x0 += k1;  x1 += ks2 + 4u;
  TFR(13) TFR(15) TFR(26) TFR(6)   x0 += ks2; x1 += k0 + 5u;
#undef TFR
  *o0 = x0; *o1 = x1;
}

// fp32 -> bf16 with round-to-nearest-even (matches XLA convert semantics).
__device__ __forceinline__ unsigned f2bf(float f) {
  unsigned b = __float_as_uint(f);
  return (b + 0x7fffu + ((b >> 16) & 1u)) >> 16;
}
__device__ __forceinline__ float bf2f(unsigned hi) {
  return __uint_as_float(hi << 16);
}

// ---------------------------------------------------------------------------
// CSR build. R3: monotone starts via 3-kernel scan + XCD-range-partitioned
// fill (WRITE 107→70 MB). R4: the remaining 70 MB is dirty-colbuf-line
// eviction caused by the 8× streaming dst/src re-reads flowing through the
// same L2 → make edge reads NON-TEMPORAL so they don't evict the write lines.
// ---------------------------------------------------------------------------
__global__ __launch_bounds__(THREADS) void compute_deg(const int* __restrict__ dst,
                                                       int* __restrict__ deg, int E) {
  int e = blockIdx.x * THREADS + threadIdx.x;
  if (e < E) atomicAdd(&deg[__builtin_nontemporal_load(dst + e)], 1);
}

// scan1: per-block local exclusive scan of deg into start; block total → blksum.
__global__ __launch_bounds__(THREADS) void scan1_local(const int* __restrict__ deg,
                                                       int* __restrict__ start,
                                                       int* __restrict__ blksum, int n) {
  __shared__ int sdata[THREADS];
  int i = blockIdx.x * THREADS + threadIdx.x;
  int d = (i < n) ? deg[i] : 0;
  sdata[threadIdx.x] = d;
  __syncthreads();
  for (int off = 1; off < THREADS; off <<= 1) {
    int v = (threadIdx.x >= off) ? sdata[threadIdx.x - off] : 0;
    __syncthreads();
    sdata[threadIdx.x] += v;
    __syncthreads();
  }
  if (i < n) start[i] = sdata[threadIdx.x] - d;  // local exclusive
  if (threadIdx.x == THREADS - 1) blksum[blockIdx.x] = sdata[THREADS - 1];
}

// scan2: ONE block (512 thr) exclusive-scans the <=512 block sums.
__global__ __launch_bounds__(512) void scan2_blocks(const int* __restrict__ blksum,
                                                    int* __restrict__ blkbase, int nb) {
  __shared__ int sdata[512];
  int t = threadIdx.x;
  int v = (t < nb) ? blksum[t] : 0;
  sdata[t] = v;
  __syncthreads();
  for (int off = 1; off < 512; off <<= 1) {
    int u = (t >= off) ? sdata[t - off] : 0;
    __syncthreads();
    sdata[t] += u;
    __syncthreads();
  }
  if (t < nb) blkbase[t] = sdata[t] - v;  // exclusive
}

// scan3: start[i] += blkbase[block]  → globally monotone exclusive starts.
__global__ __launch_bounds__(THREADS) void scan3_add(int* __restrict__ start,
                                                     const int* __restrict__ blkbase,
                                                     int n) {
  int i = blockIdx.x * THREADS + threadIdx.x;
  if (i < n) start[i] += blkbase[blockIdx.x];
}

// XCD-range-partitioned fill; group g = blockIdx&7 handles dst range g only.
__global__ __launch_bounds__(THREADS) void fill_csr_xcd(const int* __restrict__ src,
                                                        const int* __restrict__ dst,
                                                        const int* __restrict__ start,
                                                        int* __restrict__ fill,
                                                        int* __restrict__ colbuf,
                                                        int E, int rngw) {
  int g = blockIdx.x & 7;
  int chunk = blockIdx.x >> 3;
  int nchunk = gridDim.x >> 3;
  int lo = g * rngw, hi = lo + rngw;
  int stride = nchunk * THREADS;
  for (int e = chunk * THREADS + threadIdx.x; e < E; e += stride) {
    int d = __builtin_nontemporal_load(dst + e);
    if (d >= lo && d < hi) {
      int s = __builtin_nontemporal_load(src + e);
      int p = atomicAdd(&fill[d], 1);
      colbuf[start[d] + p] = s;
    }
  }
}

// ---------------------------------------------------------------------------
// Pack [Wl | Wr] (each 128x128 fp32, k-major) into MFMA B-fragment order:
// uint4 idx ((nt*4+kc)*4+quad)*16 + n  holds bf16 B[k=kc*32+quad*8+j][col],
// j=0..7 (pairs lo|hi<<16), col = nt<8 ? nt*16+n (Wl) : (nt-8)*16+n (Wr).
// One-time (~256 KB strided fp32 reads); makes the GEMM's B-loads perfectly
// lane-coalesced 16 B reads of a 64 KB L2-resident buffer.
// ---------------------------------------------------------------------------
__global__ __launch_bounds__(THREADS) void pack_weights(const float* __restrict__ Wl,
                                                        const float* __restrict__ Wr,
                                                        uint4* __restrict__ Wp) {
  int idx = blockIdx.x * THREADS + threadIdx.x;   // 0..4095
  int n = idx & 15, quad = (idx >> 4) & 3, kc = (idx >> 6) & 3, nt = idx >> 8;
  const float* W = (nt < 8) ? Wl : Wr;
  int col = ((nt & 7) * 16) + n;
  int k0 = kc * 32 + quad * 8;
  unsigned u[4];
#pragma unroll
  for (int p = 0; p < 4; ++p) {
    unsigned lo = f2bf(W[(size_t)(k0 + 2 * p) * 128 + col]);
    unsigned hi = f2bf(W[(size_t)(k0 + 2 * p + 1) * 128 + col]);
    u[p] = lo | (hi << 16);
  }
  Wp[idx] = make_uint4(u[0], u[1], u[2], u[3]);
}

// ---------------------------------------------------------------------------
// Fused dual GEMM via MFMA bf16: Cl = bf16(A@Wl), Cr = A@Wr + bias.
// R4 post-mortem: fp32 vector gemm128 was LDS-conflict bound (400K conflicts,
// VALU 35%, 91 µs ×4). This kernel uses NO LDS: A-frags live in 16 VGPRs
// (fp32→bf16 RNE pack on load), B-frags stream from the packed L2-resident
// weights. Wave owns 16 rows × 256 cols = 16 n-tiles × 4 k-chunks of
// mfma_f32_16x16x32_bf16. In-place-safe on Cr==A (wave reads only its own
// rows, fully, before any store).
// A-frag: A[m=lane&15][k=quad*8+j]; C/D: col=lane&15, row=quad*4+reg  [guide §3]
// ---------------------------------------------------------------------------
__global__ __launch_bounds__(THREADS) void gemm_dual_mfma(
    const float* A, const uint4* __restrict__ Wp, const float* __restrict__ bias,
    unsigned short* __restrict__ Cl, float* __restrict__ Cr, int M) {
  int t = threadIdx.x;
  int wv = t >> 6;
  int lane = t & 63;
  int m16 = lane & 15;
  int quad = lane >> 4;
  int arow = blockIdx.x * 64 + wv * 16 + m16;     // A row this lane feeds
  bool avalid = arow < M;

  union U8 { uint4 u; bf16x8 v; };

  // Load + pack A fragments: 4 k-chunks × 8 fp32 → 4 × bf16x8 (16 VGPRs)
  bf16x8 af[4];
  const float* ap = A + (size_t)arow * 128 + quad * 8;
#pragma unroll
  for (int kc = 0; kc < 4; ++kc) {
    float4 v0 = make_float4(0.f, 0.f, 0.f, 0.f), v1 = v0;
    if (avalid) {
      v0 = *(const float4*)(ap + kc * 32);
      v1 = *(const float4*)(ap + kc * 32 + 4);
    }
    U8 u;
    u.u.x = f2bf(v0.x) | (f2bf(v0.y) << 16);
    u.u.y = f2bf(v0.z) | (f2bf(v0.w) << 16);
    u.u.z = f2bf(v1.x) | (f2bf(v1.y) << 16);
    u.u.w = f2bf(v1.z) | (f2bf(v1.w) << 16);
    af[kc] = u.v;
  }

  f32x4 acc[16];
#pragma unroll
  for (int nt = 0; nt < 16; ++nt) acc[nt] = (f32x4){0.f, 0.f, 0.f, 0.f};

  const uint4* wp = Wp + m16;   // + ((nt*4+kc)*4+quad)*16
#pragma unroll
  for (int nt = 0; nt < 16; ++nt) {
#pragma unroll
    for (int kc = 0; kc < 4; ++kc) {
      U8 b;
      b.u = wp[((nt * 4 + kc) * 4 + quad) * 16];
      acc[nt] = __builtin_amdgcn_mfma_f32_16x16x32_bf16(af[kc], b.v, acc[nt], 0, 0, 0);
    }
  }

  // Epilogue: tiles 0..7 → Cl (bf16), 8..15 → Cr (fp32 + bias).
  int orow0 = blockIdx.x * 64 + wv * 16 + quad * 4;
#pragma unroll
  for (int nt = 0; nt < 8; ++nt) {
    int col = nt * 16 + m16;
#pragma unroll
    for (int r = 0; r < 4; ++r) {
      int row = orow0 + r;
      if (row < M) Cl[(size_t)row * 128 + col] = (unsigned short)f2bf(acc[nt][r]);
    }
  }
#pragma unroll
  for (int nt = 8; nt < 16; ++nt) {
    int col = (nt - 8) * 16 + m16;
    float bb = bias[col];
#pragma unroll
    for (int r = 0; r < 4; ++r) {
      int row = orow0 + r;
      if (row < M) Cr[(size_t)row * 128 + col] = acc[nt][r] + bb;
    }
  }
}

// ---------------------------------------------------------------------------
// Fused layer-3 projections: Cl = bf16(A@Wl), Cr = A@Wr + br. Reads A ONCE.
// (R1: split gemm16 hit a 256-VGPR spill cliff; this form holds 2 accs.)
// ---------------------------------------------------------------------------
__global__ __launch_bounds__(THREADS) void gemm16_dual(const float* __restrict__ A,
                                                       const float* __restrict__ Wl,
                                                       const float* __restrict__ Wr,
                                                       const float* __restrict__ br,
                                                       unsigned short* __restrict__ Cl,
                                                       float* __restrict__ Cr, int M) {
  __shared__ __align__(16) float Wls[128][16];  // [k][col]
  __shared__ __align__(16) float Wrs[128][16];
  __shared__ __align__(16) float As[16][130];   // [row][k], +2 pad
  int t = threadIdx.x;
#pragma unroll
  for (int i = 0; i < 2; ++i) {
    int lin = (t + i * THREADS) << 2;           // float4 id → float offset
    *(float4*)&Wls[0][lin & 2047] = *(const float4*)(Wl + lin);
    *(float4*)&Wrs[0][lin & 2047] = *(const float4*)(Wr + lin);
  }
  int row0 = blockIdx.x * 16;
  int r = t >> 4;     // 0..15 local row
  int c = t & 15;     // col / chunk id
  {
    int grow = row0 + r;
    float4 v0 = make_float4(0.f, 0.f, 0.f, 0.f), v1 = v0;
    if (grow < M) {
      const float* ap = A + (size_t)grow * 128 + c * 8;
      v0 = *(const float4*)(ap);
      v1 = *(const float4*)(ap + 4);
    }
    *(float4*)&As[r][c * 8] = v0;
    *(float4*)&As[r][c * 8 + 4] = v1;
  }
  __syncthreads();
  float accl = 0.f, accr = 0.f;
#pragma unroll 4
  for (int k = 0; k < 128; ++k) {
    float a = As[r][k];                          // broadcast across 16 lanes
    accl += a * Wls[k][c];
    accr += a * Wrs[k][c];
  }
  int grow = row0 + r;
  if (grow < M) {
    Cl[(size_t)grow * 16 + c] = (unsigned short)f2bf(accl);
    Cr[(size_t)grow * 16 + c] = accr + br[c];
  }
}

// ---------------------------------------------------------------------------
// Z[n] += agg(Ybf16)[n] / max(deg,1): one wave per node, uint (2 bf16 cols)
// per lane, edges unrolled ×4 (R3: latency×TLP bound → 4 gathers in flight).
// ---------------------------------------------------------------------------
__global__ __launch_bounds__(THREADS) void aggregate128_bf16(
    const unsigned short* __restrict__ Y, float* __restrict__ Z,
    const int* __restrict__ colbuf, const int* __restrict__ start,
    const int* __restrict__ deg, int nnodes) {
  int w = (blockIdx.x * THREADS + threadIdx.x) >> 6;  // node = global wave id
  int lane = threadIdx.x & 63;
  if (w >= nnodes) return;
  const int* cb = colbuf + start[w];
  int dg = deg[w];
  const unsigned short* yp = Y + (lane << 1);
  float ax = 0.f, ay = 0.f;
  int i = 0;
  for (; i + 4 <= dg; i += 4) {
    int e0 = cb[i], e1 = cb[i + 1], e2 = cb[i + 2], e3 = cb[i + 3];
    unsigned u0 = *(const unsigned*)(yp + (size_t)e0 * 128);
    unsigned u1 = *(const unsigned*)(yp + (size_t)e1 * 128);
    unsigned u2 = *(const unsigned*)(yp + (size_t)e2 * 128);
    unsigned u3 = *(const unsigned*)(yp + (size_t)e3 * 128);
    ax += __uint_as_float(u0 << 16);
    ay += __uint_as_float(u0 & 0xffff0000u);
    ax += __uint_as_float(u1 << 16);
    ay += __uint_as_float(u1 & 0xffff0000u);
    ax += __uint_as_float(u2 << 16);
    ay += __uint_as_float(u2 & 0xffff0000u);
    ax += __uint_as_float(u3 << 16);
    ay += __uint_as_float(u3 & 0xffff0000u);
  }
  for (; i < dg; ++i) {
    unsigned u = *(const unsigned*)(yp + (size_t)cb[i] * 128);
    ax += __uint_as_float(u << 16);
    ay += __uint_as_float(u & 0xffff0000u);
  }
  float sc = 1.0f / fmaxf((float)dg, 1.0f);
  size_t off = (size_t)w * 128 + (lane << 1);
  float2 z = *(const float2*)(Z + off);
  z.x += ax * sc;
  z.y += ay * sc;
  *(float2*)(Z + off) = z;
}

// Out[n] += agg(Y16bf16)[n] / max(deg,1): 8 threads/node, ×4 edge unroll.
__global__ __launch_bounds__(THREADS) void aggregate16_bf16(
    const unsigned short* __restrict__ Y, float* __restrict__ Out,
    const int* __restrict__ colbuf, const int* __restrict__ start,
    const int* __restrict__ deg, int nnodes) {
  int gid = blockIdx.x * THREADS + threadIdx.x;
  int n = gid >> 3;
  int cp = gid & 7;             // col pair: cols 2cp, 2cp+1
  if (n >= nnodes) return;
  const int* cb = colbuf + start[n];
  int dg = deg[n];
  const unsigned short* yp = Y + (cp << 1);
  float ax = 0.f, ay = 0.f;
  int i = 0;
  for (; i + 4 <= dg; i += 4) {
    int e0 = cb[i], e1 = cb[i + 1], e2 = cb[i + 2], e3 = cb[i + 3];
    unsigned u0 = *(const unsigned*)(yp + (size_t)e0 * 16);
    unsigned u1 = *(const unsigned*)(yp + (size_t)e1 * 16);
    unsigned u2 = *(const unsigned*)(yp + (size_t)e2 * 16);
    unsigned u3 = *(const unsigned*)(yp + (size_t)e3 * 16);
    ax += __uint_as_float(u0 << 16);
    ay += __uint_as_float(u0 & 0xffff0000u);
    ax += __uint_as_float(u1 << 16);
    ay += __uint_as_float(u1 & 0xffff0000u);
    ax += __uint_as_float(u2 << 16);
    ay += __uint_as_float(u2 & 0xffff0000u);
    ax += __uint_as_float(u3 << 16);
    ay += __uint_as_float(u3 & 0xffff0000u);
  }
  for (; i < dg; ++i) {
    unsigned u = *(const unsigned*)(yp + (size_t)cb[i] * 16);
    ax += __uint_as_float(u << 16);
    ay += __uint_as_float(u & 0xffff0000u);
  }
  float sc = 1.0f / fmaxf((float)dg, 1.0f);
  size_t off = (size_t)n * 16 + (cp << 1);
  float2 o = *(const float2*)(Out + off);
  o.x += ax * sc;
  o.y += ay * sc;
  *(float2*)(Out + off) = o;
}

// ---------------------------------------------------------------------------
// BN: column sums/sumsq → scale/shift → fused affine+ReLU+dropout (in place).
// ---------------------------------------------------------------------------
__global__ __launch_bounds__(THREADS) void bn_stats(const float* __restrict__ H,
                                                    float* __restrict__ sums, int n) {
  int col = threadIdx.x & 127;
  int half = threadIdx.x >> 7;  // 0/1
  float s = 0.f, sq = 0.f;
  for (int r = blockIdx.x * 2 + half; r < n; r += gridDim.x * 2) {
    float v = H[(size_t)r * 128 + col];
    s += v;
    sq += v * v;
  }
  __shared__ float ls[THREADS], lq[THREADS];
  ls[threadIdx.x] = s;
  lq[threadIdx.x] = sq;
  __syncthreads();
  if (half == 0) {
    s += ls[col + 128];
    sq += lq[col + 128];
    atomicAdd(&sums[col], s);
    atomicAdd(&sums[128 + col], sq);
  }
}

__global__ void bn_finalize(const float* __restrict__ sums,
                            const float* __restrict__ g,
                            const float* __restrict__ be,
                            float* __restrict__ scsh, float n) {
  int c = threadIdx.x;  // 128 threads
  float mu = sums[c] / n;
  float var = sums[128 + c] / n - mu * mu;
  float inv = rsqrtf(var + 1e-5f);
  float sc = g[c] * inv;
  scsh[c] = sc;
  scsh[128 + c] = be[c] - mu * sc;
}

// keep[i] = msb(o0^o1 of tf(key,(0,i))) == 0  (uniform<0.5, partitionable).
// H[i] = keep ? 2*relu(H[i]*scale+shift) : 0. Two elements (float2) / thread.
__global__ __launch_bounds__(THREADS) void bn_relu_dropout(float* __restrict__ H,
                                                           const float* __restrict__ scsh,
                                                           unsigned k0, unsigned k1,
                                                           int count2) {
  int j = blockIdx.x * THREADS + threadIdx.x;  // element pair id
  if (j >= count2) return;
  unsigned i0 = (unsigned)j << 1;
  unsigned a0, a1, b0, b1;
  tf2x32(k0, k1, 0u, i0, &a0, &a1);
  tf2x32(k0, k1, 0u, i0 + 1u, &b0, &b1);
  int col = (int)(i0 & 127u);  // even
  float2 v = *(float2*)(H + i0);
  float s0 = scsh[col], sh0 = scsh[128 + col];
  float s1 = scsh[col + 1], sh1 = scsh[129 + col];
  v.x = fmaxf(v.x * s0 + sh0, 0.f);
  v.y = fmaxf(v.y * s1 + sh1, 0.f);
  v.x = ((a0 ^ a1) >> 31) ? 0.f : 2.f * v.x;
  v.y = ((b0 ^ b1) >> 31) ? 0.f : 2.f * v.y;
  *(float2*)(H + i0) = v;
}

// ---------------------------------------------------------------------------
// Launch: pack weights once; CSR (deg → scan → XCD fill, nt edge reads);
// per layer ONE fused MFMA dual GEMM (Cl bf16 → buf0, Cr fp32+b → buf1),
// unrolled bf16 gather-agg into buf1, BN, fused BN+ReLU+dropout.
// Layer-3: fused dual 16-wide GEMM then bf16 aggregate.
// ---------------------------------------------------------------------------
extern "C" void kernel_launch(void* const* d_in, const int* in_sizes, int n_in,
                              void* d_out, int out_size, void* d_ws, size_t ws_size,
                              hipStream_t stream) {
  const float* x   = (const float*)d_in[0];
  const int* eidx  = (const int*)d_in[1];
  const float* W1l = (const float*)d_in[2];
  const float* W1r = (const float*)d_in[3];
  const float* b1  = (const float*)d_in[4];
  const float* g1  = (const float*)d_in[5];
  const float* be1 = (const float*)d_in[6];
  const float* W2l = (const float*)d_in[7];
  const float* W2r = (const float*)d_in[8];
  const float* b2  = (const float*)d_in[9];
  const float* g2  = (const float*)d_in[10];
  const float* be2 = (const float*)d_in[11];
  const float* W3l = (const float*)d_in[12];
  const float* W3r = (const float*)d_in[13];
  const float* b3  = (const float*)d_in[14];
  float* out = (float*)d_out;

  const int N = in_sizes[0] / 128;
  const int E = in_sizes[1] / 2;
  const int* esrc = eidx;
  const int* edst = eidx + E;

  size_t N128 = (size_t)N * 128;
  float* buf0 = (float*)d_ws;                 // holds bf16 N×128 (uses half)
  float* buf1 = buf0 + N128;
  float* sums = buf1 + N128;
  float* scsh = sums + 256;
  int* ideg   = (int*)(scsh + 256);
  int* istart = ideg + N;
  int* ifill  = istart + N;
  int* iblksum = ifill + N;                   // 512
  int* iblkbase = iblksum + 512;              // 512
  uint4* wp1 = (uint4*)(iblkbase + 512);      // 16384 uint4 = 64 KB
  uint4* wp2 = wp1 + 4096;
  int* icol   = (int*)(wp2 + 4096);
  unsigned short* buf0h = (unsigned short*)buf0;

  // dropout keys: k1,k2 = split(key(42)) under partitionable threefry
  unsigned k1a, k1b, k2a, k2b;
  tf2x32(0u, 42u, 0u, 0u, &k1a, &k1b);
  tf2x32(0u, 42u, 0u, 1u, &k2a, &k2b);

  hipMemsetAsync(ideg, 0, (size_t)N * 4, stream);
  hipMemsetAsync(ifill, 0, (size_t)N * 4, stream);

  pack_weights<<<16, THREADS, 0, stream>>>(W1l, W1r, wp1);
  pack_weights<<<16, THREADS, 0, stream>>>(W2l, W2r, wp2);

  int gE = (E + THREADS - 1) / THREADS;
  int gN = (N + THREADS - 1) / THREADS;      // == #scan blocks, must be <=512
  compute_deg<<<gE, THREADS, 0, stream>>>(edst, ideg, E);
  scan1_local<<<gN, THREADS, 0, stream>>>(ideg, istart, iblksum, N);
  scan2_blocks<<<1, 512, 0, stream>>>(iblksum, iblkbase, gN);
  scan3_add<<<gN, THREADS, 0, stream>>>(istart, iblkbase, N);
  int rngw = (N + 7) / 8;
  fill_csr_xcd<<<512, THREADS, 0, stream>>>(esrc, edst, istart, ifill, icol, E, rngw);

  int gM64 = (N + 63) / 64;
  int gW = (N + 3) / 4;                 // aggregate128: 4 waves/block
  int half2 = (int)(N128 / 2);
  int gD = (half2 + THREADS - 1) / THREADS;
  int gA16 = (N * 8 + THREADS - 1) / THREADS;

  // ---- Layer 1 ----
  gemm_dual_mfma<<<gM64, THREADS, 0, stream>>>(x, wp1, b1, buf0h, buf1, N);
  aggregate128_bf16<<<gW, THREADS, 0, stream>>>(buf0h, buf1, icol, istart, ideg, N);
  hipMemsetAsync(sums, 0, 256 * 4, stream);
  bn_stats<<<200, THREADS, 0, stream>>>(buf1, sums, N);
  bn_finalize<<<1, 128, 0, stream>>>(sums, g1, be1, scsh, (float)N);
  bn_relu_dropout<<<gD, THREADS, 0, stream>>>(buf1, scsh, k1a, k1b, half2);

  // ---- Layer 2 (Cr in-place on buf1: wave reads its rows before storing) ----
  gemm_dual_mfma<<<gM64, THREADS, 0, stream>>>(buf1, wp2, b2, buf0h, buf1, N);
  aggregate128_bf16<<<gW, THREADS, 0, stream>>>(buf0h, buf1, icol, istart, ideg, N);
  hipMemsetAsync(sums, 0, 256 * 4, stream);
  bn_stats<<<200, THREADS, 0, stream>>>(buf1, sums, N);
  bn_finalize<<<1, 128, 0, stream>>>(sums, g2, be2, scsh, (float)N);
  bn_relu_dropout<<<gD, THREADS, 0, stream>>>(buf1, scsh, k2a, k2b, half2);

  // ---- Layer 3 (fused dual 16-wide GEMM, then bf16 aggregate) ----
  gemm16_dual<<<(N + 15) / 16, THREADS, 0, stream>>>(buf1, W3l, W3r, b3, buf0h, out, N);
  aggregate16_bf16<<<gA16, THREADS, 0, stream>>>(buf0h, out, icol, istart, ideg, N);
}

// Round 6
// 705.179 us; speedup vs baseline: 2.5267x; 1.1302x over previous
//
#include <hip/hip_runtime.h>
#include <cstdint>
#include <cstddef>

#define THREADS 256

typedef __attribute__((ext_vector_type(8))) short bf16x8;
typedef __attribute__((ext_vector_type(4))) float f32x4;

// ---------------------------------------------------------------------------
// JAX threefry2x32 (Random123, 20 rounds) — used for the dropout masks.
// jax_threefry_partitionable=True semantics (verified R1: absmax 0.0156):
// split keys = tf(key,(0,j)); bits[i] = o0^o1 of tf(key,(0,i)).
// ---------------------------------------------------------------------------
__host__ __device__ __forceinline__ void tf2x32(unsigned k0, unsigned k1,
                                                unsigned x0, unsigned x1,
                                                unsigned* o0, unsigned* o1) {
  unsigned ks2 = k0 ^ k1 ^ 0x1BD11BDAu;
  x0 += k0; x1 += k1;
#define TFR(r) { x0 += x1; x1 = (x1 << (r)) | (x1 >> (32 - (r))); x1 ^= x0; }
  TFR(13) TFR(15) TFR(26) TFR(6)   x0 += k1;  x1 += ks2 + 1u;
  TFR(17) TFR(29) TFR(16) TFR(24)  x0 += ks2; x1 += k0 + 2u;
  TFR(13) TFR(15) TFR(26) TFR(6)   x0 += k0;  x1 += k1 + 3u;
  TFR(17) TFR(29) TFR(16) TFR(24)  x0 += k1;  x1 += ks2 + 4u;
  TFR(13) TFR(15) TFR(26) TFR(6)   x0 += ks2; x1 += k0 + 5u;
#undef TFR
  *o0 = x0; *o1 = x1;
}

// fp32 -> bf16 with round-to-nearest-even (matches XLA convert semantics).
__device__ __forceinline__ unsigned f2bf(float f) {
  unsigned b = __float_as_uint(f);
  return (b + 0x7fffu + ((b >> 16) & 1u)) >> 16;
}

// Fused BN-affine + ReLU + dropout on 8 consecutive elements of one row.
// Bit-identical to the old standalone bn_relu_dropout (even pair alignment:
// col0 is always a multiple of 8).
__device__ __forceinline__ void bn_drop8(float* v, const float* __restrict__ scsh,
                                         int col0, unsigned ibase,
                                         unsigned dk0, unsigned dk1) {
  float4 s0 = *(const float4*)(scsh + col0);
  float4 s1 = *(const float4*)(scsh + col0 + 4);
  float4 h0 = *(const float4*)(scsh + 128 + col0);
  float4 h1 = *(const float4*)(scsh + 128 + col0 + 4);
  float sc[8] = {s0.x, s0.y, s0.z, s0.w, s1.x, s1.y, s1.z, s1.w};
  float sh[8] = {h0.x, h0.y, h0.z, h0.w, h1.x, h1.y, h1.z, h1.w};
#pragma unroll
  for (int p = 0; p < 4; ++p) {
    unsigned a0, a1, b0, b1;
    tf2x32(dk0, dk1, 0u, ibase + 2 * p, &a0, &a1);
    tf2x32(dk0, dk1, 0u, ibase + 2 * p + 1, &b0, &b1);
    float t0 = fmaxf(v[2 * p] * sc[2 * p] + sh[2 * p], 0.f);
    float t1 = fmaxf(v[2 * p + 1] * sc[2 * p + 1] + sh[2 * p + 1], 0.f);
    v[2 * p] = ((a0 ^ a1) >> 31) ? 0.f : 2.f * t0;
    v[2 * p + 1] = ((b0 ^ b1) >> 31) ? 0.f : 2.f * t1;
  }
}

// ---------------------------------------------------------------------------
// CSR build. R3: monotone starts (3-kernel scan) + XCD-range-partitioned fill.
// R5 post-mortem: nontemporal edge reads REGRESSED (93→126 µs) — latency-
// bound, and the 512-block grid was only 1/4 of wave capacity. Revert nt,
// grid → 2048 blocks (8192 waves = full device).
// ---------------------------------------------------------------------------
__global__ __launch_bounds__(THREADS) void compute_deg(const int* __restrict__ dst,
                                                       int* __restrict__ deg, int E) {
  int e = blockIdx.x * THREADS + threadIdx.x;
  if (e < E) atomicAdd(&deg[dst[e]], 1);
}

// scan1: per-block local exclusive scan of deg into start; block total → blksum.
__global__ __launch_bounds__(THREADS) void scan1_local(const int* __restrict__ deg,
                                                       int* __restrict__ start,
                                                       int* __restrict__ blksum, int n) {
  __shared__ int sdata[THREADS];
  int i = blockIdx.x * THREADS + threadIdx.x;
  int d = (i < n) ? deg[i] : 0;
  sdata[threadIdx.x] = d;
  __syncthreads();
  for (int off = 1; off < THREADS; off <<= 1) {
    int v = (threadIdx.x >= off) ? sdata[threadIdx.x - off] : 0;
    __syncthreads();
    sdata[threadIdx.x] += v;
    __syncthreads();
  }
  if (i < n) start[i] = sdata[threadIdx.x] - d;  // local exclusive
  if (threadIdx.x == THREADS - 1) blksum[blockIdx.x] = sdata[THREADS - 1];
}

// scan2: ONE block (512 thr) exclusive-scans the <=512 block sums.
__global__ __launch_bounds__(512) void scan2_blocks(const int* __restrict__ blksum,
                                                    int* __restrict__ blkbase, int nb) {
  __shared__ int sdata[512];
  int t = threadIdx.x;
  int v = (t < nb) ? blksum[t] : 0;
  sdata[t] = v;
  __syncthreads();
  for (int off = 1; off < 512; off <<= 1) {
    int u = (t >= off) ? sdata[t - off] : 0;
    __syncthreads();
    sdata[t] += u;
    __syncthreads();
  }
  if (t < nb) blkbase[t] = sdata[t] - v;  // exclusive
}

// scan3: start[i] += blkbase[block]  → globally monotone exclusive starts.
__global__ __launch_bounds__(THREADS) void scan3_add(int* __restrict__ start,
                                                     const int* __restrict__ blkbase,
                                                     int n) {
  int i = blockIdx.x * THREADS + threadIdx.x;
  if (i < n) start[i] += blkbase[blockIdx.x];
}

// XCD-range-partitioned fill; group g = blockIdx&7 handles dst range g only.
__global__ __launch_bounds__(THREADS) void fill_csr_xcd(const int* __restrict__ src,
                                                        const int* __restrict__ dst,
                                                        const int* __restrict__ start,
                                                        int* __restrict__ fill,
                                                        int* __restrict__ colbuf,
                                                        int E, int rngw) {
  int g = blockIdx.x & 7;
  int chunk = blockIdx.x >> 3;
  int nchunk = gridDim.x >> 3;
  int lo = g * rngw, hi = lo + rngw;
  int stride = nchunk * THREADS;
  for (int e = chunk * THREADS + threadIdx.x; e < E; e += stride) {
    int d = dst[e];
    if (d >= lo && d < hi) {
      int p = atomicAdd(&fill[d], 1);
      colbuf[start[d] + p] = src[e];
    }
  }
}

// ---------------------------------------------------------------------------
// Pack [Wl | Wr] (each 128x128 fp32, k-major) into MFMA B-fragment order:
// uint4 idx ((nt*4+kc)*4+quad)*16 + n  holds bf16 B[k=kc*32+quad*8+j][col],
// j=0..7 (pairs lo|hi<<16), col = nt<8 ? nt*16+n (Wl) : (nt-8)*16+n (Wr).
// ---------------------------------------------------------------------------
__global__ __launch_bounds__(THREADS) void pack_weights(const float* __restrict__ Wl,
                                                        const float* __restrict__ Wr,
                                                        uint4* __restrict__ Wp) {
  int idx = blockIdx.x * THREADS + threadIdx.x;   // 0..4095
  int n = idx & 15, quad = (idx >> 4) & 3, kc = (idx >> 6) & 3, nt = idx >> 8;
  const float* W = (nt < 8) ? Wl : Wr;
  int col = ((nt & 7) * 16) + n;
  int k0 = kc * 32 + quad * 8;
  unsigned u[4];
#pragma unroll
  for (int p = 0; p < 4; ++p) {
    unsigned lo = f2bf(W[(size_t)(k0 + 2 * p) * 128 + col]);
    unsigned hi = f2bf(W[(size_t)(k0 + 2 * p + 1) * 128 + col]);
    u[p] = lo | (hi << 16);
  }
  Wp[idx] = make_uint4(u[0], u[1], u[2], u[3]);
}

// ---------------------------------------------------------------------------
// Fused dual GEMM via MFMA bf16: Cl = bf16(A'@Wl), Cr = A'@Wr + bias, where
// A' = FUSE ? dropout(relu(bn_affine(A))) : A  — the BN+ReLU+dropout of the
// PREVIOUS layer fused into this GEMM's A-load (saves the 102 MB round trip
// of the standalone bn_relu_dropout kernel; threefry VALU co-schedules with
// MFMA). No LDS; B-frags stream from packed L2-resident weights.
// In-place-safe on Cr==A (wave reads only its own rows fully before storing).
// A-frag: A[m=lane&15][k=quad*8+j]; C/D: col=lane&15, row=quad*4+reg.
// ---------------------------------------------------------------------------
template <int FUSE>
__global__ __launch_bounds__(THREADS) void gemm_dual_mfma(
    const float* A, const uint4* __restrict__ Wp, const float* __restrict__ bias,
    const float* __restrict__ scsh, unsigned dk0, unsigned dk1,
    unsigned short* __restrict__ Cl, float* __restrict__ Cr, int M) {
  int t = threadIdx.x;
  int wv = t >> 6;
  int lane = t & 63;
  int m16 = lane & 15;
  int quad = lane >> 4;
  int arow = blockIdx.x * 64 + wv * 16 + m16;     // A row this lane feeds
  bool avalid = arow < M;

  union U8 { uint4 u; bf16x8 v; };

  // Load (+ optionally transform) + pack A fragments: 4 k-chunks × 8 fp32.
  bf16x8 af[4];
  const float* ap = A + (size_t)arow * 128 + quad * 8;
#pragma unroll
  for (int kc = 0; kc < 4; ++kc) {
    float v[8] = {0.f, 0.f, 0.f, 0.f, 0.f, 0.f, 0.f, 0.f};
    if (avalid) {
      *(float4*)&v[0] = *(const float4*)(ap + kc * 32);
      *(float4*)&v[4] = *(const float4*)(ap + kc * 32 + 4);
    }
    if (FUSE) {
      int col0 = kc * 32 + quad * 8;
      bn_drop8(v, scsh, col0, (unsigned)arow * 128u + (unsigned)col0, dk0, dk1);
    }
    U8 u;
    u.u.x = f2bf(v[0]) | (f2bf(v[1]) << 16);
    u.u.y = f2bf(v[2]) | (f2bf(v[3]) << 16);
    u.u.z = f2bf(v[4]) | (f2bf(v[5]) << 16);
    u.u.w = f2bf(v[6]) | (f2bf(v[7]) << 16);
    af[kc] = u.v;
  }

  f32x4 acc[16];
#pragma unroll
  for (int nt = 0; nt < 16; ++nt) acc[nt] = (f32x4){0.f, 0.f, 0.f, 0.f};

  const uint4* wp = Wp + m16;   // + ((nt*4+kc)*4+quad)*16
#pragma unroll
  for (int nt = 0; nt < 16; ++nt) {
#pragma unroll
    for (int kc = 0; kc < 4; ++kc) {
      U8 b;
      b.u = wp[((nt * 4 + kc) * 4 + quad) * 16];
      acc[nt] = __builtin_amdgcn_mfma_f32_16x16x32_bf16(af[kc], b.v, acc[nt], 0, 0, 0);
    }
  }

  // Epilogue: tiles 0..7 → Cl (bf16), 8..15 → Cr (fp32 + bias).
  int orow0 = blockIdx.x * 64 + wv * 16 + quad * 4;
#pragma unroll
  for (int nt = 0; nt < 8; ++nt) {
    int col = nt * 16 + m16;
#pragma unroll
    for (int r = 0; r < 4; ++r) {
      int row = orow0 + r;
      if (row < M) Cl[(size_t)row * 128 + col] = (unsigned short)f2bf(acc[nt][r]);
    }
  }
#pragma unroll
  for (int nt = 8; nt < 16; ++nt) {
    int col = (nt - 8) * 16 + m16;
    float bb = bias[col];
#pragma unroll
    for (int r = 0; r < 4; ++r) {
      int row = orow0 + r;
      if (row < M) Cr[(size_t)row * 128 + col] = acc[nt][r] + bb;
    }
  }
}

// ---------------------------------------------------------------------------
// Fused layer-3 projections: Cl = bf16(A'@Wl), Cr = A'@Wr + br, where
// A' = dropout2(relu(bn2_affine(A))) applied on load. Reads A ONCE.
// ---------------------------------------------------------------------------
__global__ __launch_bounds__(THREADS) void gemm16_dual(const float* __restrict__ A,
                                                       const float* __restrict__ Wl,
                                                       const float* __restrict__ Wr,
                                                       const float* __restrict__ br,
                                                       const float* __restrict__ scsh,
                                                       unsigned dk0, unsigned dk1,
                                                       unsigned short* __restrict__ Cl,
                                                       float* __restrict__ Cr, int M) {
  __shared__ __align__(16) float Wls[128][16];  // [k][col]
  __shared__ __align__(16) float Wrs[128][16];
  __shared__ __align__(16) float As[16][130];   // [row][k], +2 pad
  int t = threadIdx.x;
#pragma unroll
  for (int i = 0; i < 2; ++i) {
    int lin = (t + i * THREADS) << 2;           // float4 id → float offset
    *(float4*)&Wls[0][lin & 2047] = *(const float4*)(Wl + lin);
    *(float4*)&Wrs[0][lin & 2047] = *(const float4*)(Wr + lin);
  }
  int row0 = blockIdx.x * 16;
  int r = t >> 4;     // 0..15 local row
  int c = t & 15;     // col / chunk id
  {
    int grow = row0 + r;
    float v[8] = {0.f, 0.f, 0.f, 0.f, 0.f, 0.f, 0.f, 0.f};
    if (grow < M) {
      const float* ap = A + (size_t)grow * 128 + c * 8;
      *(float4*)&v[0] = *(const float4*)(ap);
      *(float4*)&v[4] = *(const float4*)(ap + 4);
    }
    bn_drop8(v, scsh, c * 8, (unsigned)grow * 128u + (unsigned)(c * 8), dk0, dk1);
    *(float4*)&As[r][c * 8] = *(float4*)&v[0];
    *(float4*)&As[r][c * 8 + 4] = *(float4*)&v[4];
  }
  __syncthreads();
  float accl = 0.f, accr = 0.f;
#pragma unroll 4
  for (int k = 0; k < 128; ++k) {
    float a = As[r][k];                          // broadcast across 16 lanes
    accl += a * Wls[k][c];
    accr += a * Wrs[k][c];
  }
  int grow = row0 + r;
  if (grow < M) {
    Cl[(size_t)grow * 16 + c] = (unsigned short)f2bf(accl);
    Cr[(size_t)grow * 16 + c] = accr + br[c];
  }
}

// ---------------------------------------------------------------------------
// Z[n] += agg(Ybf16)[n] / max(deg,1): one wave per node, uint (2 bf16 cols)
// per lane, edges unrolled ×4 (R3: latency×TLP bound → 4 gathers in flight).
// ---------------------------------------------------------------------------
__global__ __launch_bounds__(THREADS) void aggregate128_bf16(
    const unsigned short* __restrict__ Y, float* __restrict__ Z,
    const int* __restrict__ colbuf, const int* __restrict__ start,
    const int* __restrict__ deg, int nnodes) {
  int w = (blockIdx.x * THREADS + threadIdx.x) >> 6;  // node = global wave id
  int lane = threadIdx.x & 63;
  if (w >= nnodes) return;
  const int* cb = colbuf + start[w];
  int dg = deg[w];
  const unsigned short* yp = Y + (lane << 1);
  float ax = 0.f, ay = 0.f;
  int i = 0;
  for (; i + 4 <= dg; i += 4) {
    int e0 = cb[i], e1 = cb[i + 1], e2 = cb[i + 2], e3 = cb[i + 3];
    unsigned u0 = *(const unsigned*)(yp + (size_t)e0 * 128);
    unsigned u1 = *(const unsigned*)(yp + (size_t)e1 * 128);
    unsigned u2 = *(const unsigned*)(yp + (size_t)e2 * 128);
    unsigned u3 = *(const unsigned*)(yp + (size_t)e3 * 128);
    ax += __uint_as_float(u0 << 16);
    ay += __uint_as_float(u0 & 0xffff0000u);
    ax += __uint_as_float(u1 << 16);
    ay += __uint_as_float(u1 & 0xffff0000u);
    ax += __uint_as_float(u2 << 16);
    ay += __uint_as_float(u2 & 0xffff0000u);
    ax += __uint_as_float(u3 << 16);
    ay += __uint_as_float(u3 & 0xffff0000u);
  }
  for (; i < dg; ++i) {
    unsigned u = *(const unsigned*)(yp + (size_t)cb[i] * 128);
    ax += __uint_as_float(u << 16);
    ay += __uint_as_float(u & 0xffff0000u);
  }
  float sc = 1.0f / fmaxf((float)dg, 1.0f);
  size_t off = (size_t)w * 128 + (lane << 1);
  float2 z = *(const float2*)(Z + off);
  z.x += ax * sc;
  z.y += ay * sc;
  *(float2*)(Z + off) = z;
}

// Out[n] += agg(Y16bf16)[n] / max(deg,1): 8 threads/node, ×4 edge unroll.
__global__ __launch_bounds__(THREADS) void aggregate16_bf16(
    const unsigned short* __restrict__ Y, float* __restrict__ Out,
    const int* __restrict__ colbuf, const int* __restrict__ start,
    const int* __restrict__ deg, int nnodes) {
  int gid = blockIdx.x * THREADS + threadIdx.x;
  int n = gid >> 3;
  int cp = gid & 7;             // col pair: cols 2cp, 2cp+1
  if (n >= nnodes) return;
  const int* cb = colbuf + start[n];
  int dg = deg[n];
  const unsigned short* yp = Y + (cp << 1);
  float ax = 0.f, ay = 0.f;
  int i = 0;
  for (; i + 4 <= dg; i += 4) {
    int e0 = cb[i], e1 = cb[i + 1], e2 = cb[i + 2], e3 = cb[i + 3];
    unsigned u0 = *(const unsigned*)(yp + (size_t)e0 * 16);
    unsigned u1 = *(const unsigned*)(yp + (size_t)e1 * 16);
    unsigned u2 = *(const unsigned*)(yp + (size_t)e2 * 16);
    unsigned u3 = *(const unsigned*)(yp + (size_t)e3 * 16);
    ax += __uint_as_float(u0 << 16);
    ay += __uint_as_float(u0 & 0xffff0000u);
    ax += __uint_as_float(u1 << 16);
    ay += __uint_as_float(u1 & 0xffff0000u);
    ax += __uint_as_float(u2 << 16);
    ay += __uint_as_float(u2 & 0xffff0000u);
    ax += __uint_as_float(u3 << 16);
    ay += __uint_as_float(u3 & 0xffff0000u);
  }
  for (; i < dg; ++i) {
    unsigned u = *(const unsigned*)(yp + (size_t)cb[i] * 16);
    ax += __uint_as_float(u << 16);
    ay += __uint_as_float(u & 0xffff0000u);
  }
  float sc = 1.0f / fmaxf((float)dg, 1.0f);
  size_t off = (size_t)n * 16 + (cp << 1);
  float2 o = *(const float2*)(Out + off);
  o.x += ax * sc;
  o.y += ay * sc;
  *(float2*)(Out + off) = o;
}

// ---------------------------------------------------------------------------
// BN: column sums/sumsq → scale/shift (the affine apply is fused into the
// consumer GEMM's A-load).
// ---------------------------------------------------------------------------
__global__ __launch_bounds__(THREADS) void bn_stats(const float* __restrict__ H,
                                                    float* __restrict__ sums, int n) {
  int col = threadIdx.x & 127;
  int half = threadIdx.x >> 7;  // 0/1
  float s = 0.f, sq = 0.f;
  for (int r = blockIdx.x * 2 + half; r < n; r += gridDim.x * 2) {
    float v = H[(size_t)r * 128 + col];
    s += v;
    sq += v * v;
  }
  __shared__ float ls[THREADS], lq[THREADS];
  ls[threadIdx.x] = s;
  lq[threadIdx.x] = sq;
  __syncthreads();
  if (half == 0) {
    s += ls[col + 128];
    sq += lq[col + 128];
    atomicAdd(&sums[col], s);
    atomicAdd(&sums[128 + col], sq);
  }
}

__global__ void bn_finalize(const float* __restrict__ sums,
                            const float* __restrict__ g,
                            const float* __restrict__ be,
                            float* __restrict__ scsh, float n) {
  int c = threadIdx.x;  // 128 threads
  float mu = sums[c] / n;
  float var = sums[128 + c] / n - mu * mu;
  float inv = rsqrtf(var + 1e-5f);
  float sc = g[c] * inv;
  scsh[c] = sc;
  scsh[128 + c] = be[c] - mu * sc;
}

// ---------------------------------------------------------------------------
// Launch: pack weights; CSR (deg → scan → XCD fill @2048 blocks); per layer
// ONE fused MFMA dual GEMM (with previous layer's BN+ReLU+dropout fused into
// the A-load), bf16 gather-agg, BN stats/finalize. Layer-3: fused dual
// 16-wide GEMM (BN2+drop2 on load) then bf16 aggregate.
// ---------------------------------------------------------------------------
extern "C" void kernel_launch(void* const* d_in, const int* in_sizes, int n_in,
                              void* d_out, int out_size, void* d_ws, size_t ws_size,
                              hipStream_t stream) {
  const float* x   = (const float*)d_in[0];
  const int* eidx  = (const int*)d_in[1];
  const float* W1l = (const float*)d_in[2];
  const float* W1r = (const float*)d_in[3];
  const float* b1  = (const float*)d_in[4];
  const float* g1  = (const float*)d_in[5];
  const float* be1 = (const float*)d_in[6];
  const float* W2l = (const float*)d_in[7];
  const float* W2r = (const float*)d_in[8];
  const float* b2  = (const float*)d_in[9];
  const float* g2  = (const float*)d_in[10];
  const float* be2 = (const float*)d_in[11];
  const float* W3l = (const float*)d_in[12];
  const float* W3r = (const float*)d_in[13];
  const float* b3  = (const float*)d_in[14];
  float* out = (float*)d_out;

  const int N = in_sizes[0] / 128;
  const int E = in_sizes[1] / 2;
  const int* esrc = eidx;
  const int* edst = eidx + E;

  size_t N128 = (size_t)N * 128;
  float* buf0 = (float*)d_ws;                 // holds bf16 N×128 (uses half)
  float* buf1 = buf0 + N128;
  float* sums = buf1 + N128;
  float* scsh = sums + 256;
  int* ideg   = (int*)(scsh + 256);
  int* istart = ideg + N;
  int* ifill  = istart + N;
  int* iblksum = ifill + N;                   // 512
  int* iblkbase = iblksum + 512;              // 512
  uint4* wp1 = (uint4*)(iblkbase + 512);      // 4096 uint4 each = 64 KB
  uint4* wp2 = wp1 + 4096;
  int* icol   = (int*)(wp2 + 4096);
  unsigned short* buf0h = (unsigned short*)buf0;

  // dropout keys: k1,k2 = split(key(42)) under partitionable threefry
  unsigned k1a, k1b, k2a, k2b;
  tf2x32(0u, 42u, 0u, 0u, &k1a, &k1b);
  tf2x32(0u, 42u, 0u, 1u, &k2a, &k2b);

  hipMemsetAsync(ideg, 0, (size_t)N * 4, stream);
  hipMemsetAsync(ifill, 0, (size_t)N * 4, stream);

  pack_weights<<<16, THREADS, 0, stream>>>(W1l, W1r, wp1);
  pack_weights<<<16, THREADS, 0, stream>>>(W2l, W2r, wp2);

  int gE = (E + THREADS - 1) / THREADS;
  int gN = (N + THREADS - 1) / THREADS;      // == #scan blocks, must be <=512
  compute_deg<<<gE, THREADS, 0, stream>>>(edst, ideg, E);
  scan1_local<<<gN, THREADS, 0, stream>>>(ideg, istart, iblksum, N);
  scan2_blocks<<<1, 512, 0, stream>>>(iblksum, iblkbase, gN);
  scan3_add<<<gN, THREADS, 0, stream>>>(istart, iblkbase, N);
  int rngw = (N + 7) / 8;
  fill_csr_xcd<<<2048, THREADS, 0, stream>>>(esrc, edst, istart, ifill, icol, E, rngw);

  int gM64 = (N + 63) / 64;
  int gW = (N + 3) / 4;                 // aggregate128: 4 waves/block
  int gA16 = (N * 8 + THREADS - 1) / THREADS;

  // ---- Layer 1 ----
  gemm_dual_mfma<0><<<gM64, THREADS, 0, stream>>>(x, wp1, b1, nullptr, 0u, 0u,
                                                  buf0h, buf1, N);
  aggregate128_bf16<<<gW, THREADS, 0, stream>>>(buf0h, buf1, icol, istart, ideg, N);
  hipMemsetAsync(sums, 0, 256 * 4, stream);
  bn_stats<<<200, THREADS, 0, stream>>>(buf1, sums, N);
  bn_finalize<<<1, 128, 0, stream>>>(sums, g1, be1, scsh, (float)N);

  // ---- Layer 2 (BN1+ReLU+drop1 fused into A-load; Cr in-place on buf1) ----
  gemm_dual_mfma<1><<<gM64, THREADS, 0, stream>>>(buf1, wp2, b2, scsh, k1a, k1b,
                                                  buf0h, buf1, N);
  aggregate128_bf16<<<gW, THREADS, 0, stream>>>(buf0h, buf1, icol, istart, ideg, N);
  hipMemsetAsync(sums, 0, 256 * 4, stream);
  bn_stats<<<200, THREADS, 0, stream>>>(buf1, sums, N);
  bn_finalize<<<1, 128, 0, stream>>>(sums, g2, be2, scsh, (float)N);

  // ---- Layer 3 (BN2+ReLU+drop2 fused into A-load of dual 16-wide GEMM) ----
  gemm16_dual<<<(N + 15) / 16, THREADS, 0, stream>>>(buf1, W3l, W3r, b3, scsh,
                                                     k2a, k2b, buf0h, out, N);
  aggregate16_bf16<<<gA16, THREADS, 0, stream>>>(buf0h, out, icol, istart, ideg, N);
}